// Round 1
// baseline (2921.440 us; speedup 1.0000x reference)
//
#include <hip/hip_runtime.h>
#include <hip/hip_bf16.h>
#include <stdint.h>

// CrystalGraphEncoder on MI355X — round 1: correct fp32 baseline.
// Structure: embed -> 3x { lin = x@Wl+b ; agg = scatter(gate(x_r,x_n)*lin_n) ;
//                          x = relu(agg+lin) } -> mean-pool -> 2-layer MLP.
// ws layout: x[N*64] | lin[N*64] | agg[N*64] | pool[64]  (~77 MB)

#define H 64
#define TE 64

__device__ __forceinline__ void fma4(float4& acc, const float4 a,
                                     const float4 w0, const float4 w1,
                                     const float4 w2, const float4 w3) {
  acc.x = fmaf(a.x, w0.x, acc.x); acc.y = fmaf(a.x, w0.y, acc.y);
  acc.z = fmaf(a.x, w0.z, acc.z); acc.w = fmaf(a.x, w0.w, acc.w);
  acc.x = fmaf(a.y, w1.x, acc.x); acc.y = fmaf(a.y, w1.y, acc.y);
  acc.z = fmaf(a.y, w1.z, acc.z); acc.w = fmaf(a.y, w1.w, acc.w);
  acc.x = fmaf(a.z, w2.x, acc.x); acc.y = fmaf(a.z, w2.y, acc.y);
  acc.z = fmaf(a.z, w2.z, acc.z); acc.w = fmaf(a.z, w2.w, acc.w);
  acc.x = fmaf(a.w, w3.x, acc.x); acc.y = fmaf(a.w, w3.y, acc.y);
  acc.z = fmaf(a.w, w3.z, acc.z); acc.w = fmaf(a.w, w3.w, acc.w);
}

// x[i][c] = emb[an[i]][c], float4-vectorized
__global__ void embed_kernel(const int* __restrict__ an,
                             const float* __restrict__ emb,
                             float* __restrict__ x, int N) {
  const int total = N * (H / 4);
  for (int t = blockIdx.x * blockDim.x + threadIdx.x; t < total;
       t += gridDim.x * blockDim.x) {
    const int i = t >> 4, c4 = t & 15;
    const int a = an[i];
    ((float4*)x)[t] = ((const float4*)emb)[a * 16 + c4];
  }
}

// lin = x @ W + b   (no activation), tiled 64 atoms x 64 out, K=64
__global__ __launch_bounds__(256, 4) void lin_kernel(
    const float* __restrict__ x, const float* __restrict__ W,
    const float* __restrict__ b, float* __restrict__ lin, int N) {
  __shared__ __align__(16) float xt[TE][68];   // pad 68: 2-way conflicts only
  __shared__ __align__(16) float Ws[H][H];
  const int tid = threadIdx.x;
  const int lane = tid & 63, wid = tid >> 6;
  for (int idx = tid; idx < H * H; idx += 256) Ws[idx >> 6][idx & 63] = W[idx];
  const int jb = (tid & 15) * 4, eb = (tid >> 4) * 4;
  const float4 bv = *(const float4*)(b + jb);
  for (int base = blockIdx.x * TE; base < N; base += gridDim.x * TE) {
    const int ne = min(TE, N - base);
    __syncthreads();
    for (int e = wid; e < ne; e += 4) xt[e][lane] = x[(base + e) * H + lane];
    __syncthreads();
    float4 acc0 = bv, acc1 = bv, acc2 = bv, acc3 = bv;
#pragma unroll 4
    for (int k = 0; k < H; k += 4) {
      const float4 w0 = *(const float4*)&Ws[k + 0][jb];
      const float4 w1 = *(const float4*)&Ws[k + 1][jb];
      const float4 w2 = *(const float4*)&Ws[k + 2][jb];
      const float4 w3 = *(const float4*)&Ws[k + 3][jb];
      const float4 v0 = *(const float4*)&xt[eb + 0][k];
      const float4 v1 = *(const float4*)&xt[eb + 1][k];
      const float4 v2 = *(const float4*)&xt[eb + 2][k];
      const float4 v3 = *(const float4*)&xt[eb + 3][k];
      fma4(acc0, v0, w0, w1, w2, w3);
      fma4(acc1, v1, w0, w1, w2, w3);
      fma4(acc2, v2, w0, w1, w2, w3);
      fma4(acc3, v3, w0, w1, w2, w3);
    }
    if (eb + 0 < ne) *(float4*)&lin[(base + eb + 0) * H + jb] = acc0;
    if (eb + 1 < ne) *(float4*)&lin[(base + eb + 1) * H + jb] = acc1;
    if (eb + 2 < ne) *(float4*)&lin[(base + eb + 2) * H + jb] = acc2;
    if (eb + 3 < ne) *(float4*)&lin[(base + eb + 3) * H + jb] = acc3;
  }
}

// per-edge: gate = sigmoid([x_r‖x_n] @ Wg + bg); atomicAdd(agg[row], gate*lin[col])
__global__ __launch_bounds__(256, 2) void edge_kernel(
    const float* __restrict__ x, const float* __restrict__ lin,
    const int* __restrict__ row, const int* __restrict__ col,
    const float* __restrict__ Wg, const float* __restrict__ bg,
    float* __restrict__ agg, int E) {
  __shared__ __align__(16) float gin[TE][132];  // [x_r ‖ x_n], pad 132
  __shared__ __align__(16) float Wgs[2 * H][H];
  __shared__ int rs[TE], cs[TE];
  const int tid = threadIdx.x;
  const int lane = tid & 63, wid = tid >> 6;
  for (int idx = tid; idx < 2 * H * H; idx += 256)
    Wgs[idx >> 6][idx & 63] = Wg[idx];
  const int jb = (tid & 15) * 4, eb = (tid >> 4) * 4;
  const float4 bv = *(const float4*)(bg + jb);

  for (int base = blockIdx.x * TE; base < E; base += gridDim.x * TE) {
    const int ne = min(TE, E - base);
    __syncthreads();  // previous tile fully consumed
    if (tid < ne) { rs[tid] = row[base + tid]; cs[tid] = col[base + tid]; }
    __syncthreads();
    for (int e = wid; e < ne; e += 4) {
      gin[e][lane]     = x[rs[e] * H + lane];
      gin[e][H + lane] = x[cs[e] * H + lane];
    }
    __syncthreads();
    float4 acc0 = bv, acc1 = bv, acc2 = bv, acc3 = bv;
#pragma unroll 4
    for (int k = 0; k < 2 * H; k += 4) {
      const float4 w0 = *(const float4*)&Wgs[k + 0][jb];
      const float4 w1 = *(const float4*)&Wgs[k + 1][jb];
      const float4 w2 = *(const float4*)&Wgs[k + 2][jb];
      const float4 w3 = *(const float4*)&Wgs[k + 3][jb];
      const float4 v0 = *(const float4*)&gin[eb + 0][k];
      const float4 v1 = *(const float4*)&gin[eb + 1][k];
      const float4 v2 = *(const float4*)&gin[eb + 2][k];
      const float4 v3 = *(const float4*)&gin[eb + 3][k];
      fma4(acc0, v0, w0, w1, w2, w3);
      fma4(acc1, v1, w0, w1, w2, w3);
      fma4(acc2, v2, w0, w1, w2, w3);
      fma4(acc3, v3, w0, w1, w2, w3);
    }
#pragma unroll
    for (int i = 0; i < 4; i++) {
      const int e = eb + i;
      if (e < ne) {
        float4 g = (i == 0) ? acc0 : (i == 1) ? acc1 : (i == 2) ? acc2 : acc3;
        g.x = 1.f / (1.f + __expf(-g.x));
        g.y = 1.f / (1.f + __expf(-g.y));
        g.z = 1.f / (1.f + __expf(-g.z));
        g.w = 1.f / (1.f + __expf(-g.w));
        const float4 ln = *(const float4*)(lin + cs[e] * H + jb);
        float* dst = agg + rs[e] * H + jb;
        atomicAdd(dst + 0, g.x * ln.x);
        atomicAdd(dst + 1, g.y * ln.y);
        atomicAdd(dst + 2, g.z * ln.z);
        atomicAdd(dst + 3, g.w * ln.w);
      }
    }
  }
}

// x = relu(agg + lin), elementwise float4
__global__ void update_kernel(const float* __restrict__ agg,
                              const float* __restrict__ lin,
                              float* __restrict__ x, int total4) {
  for (int t = blockIdx.x * blockDim.x + threadIdx.x; t < total4;
       t += gridDim.x * blockDim.x) {
    const float4 a = ((const float4*)agg)[t];
    const float4 l = ((const float4*)lin)[t];
    float4 r;
    r.x = fmaxf(a.x + l.x, 0.f);
    r.y = fmaxf(a.y + l.y, 0.f);
    r.z = fmaxf(a.z + l.z, 0.f);
    r.w = fmaxf(a.w + l.w, 0.f);
    ((float4*)x)[t] = r;
  }
}

// pool[c] += sum_i x[i][c]  (block partials -> one atomic per channel per block)
__global__ void pool_kernel(const float* __restrict__ x,
                            float* __restrict__ pool, int N) {
  __shared__ float ps[4][64];
  const int tid = threadIdx.x, c = tid & 63, wid = tid >> 6;
  float s = 0.f;
  for (int i = blockIdx.x * 4 + wid; i < N; i += gridDim.x * 4)
    s += x[i * H + c];
  ps[wid][c] = s;
  __syncthreads();
  if (tid < 64) {
    const float t = ps[0][tid] + ps[1][tid] + ps[2][tid] + ps[3][tid];
    atomicAdd(&pool[tid], t);
  }
}

// out = relu(pool/N @ W1 + b1) @ W2 + b2  — one block, 128 threads
__global__ void mlp_kernel(const float* __restrict__ pool,
                           const float* __restrict__ W1,
                           const float* __restrict__ b1,
                           const float* __restrict__ W2,
                           const float* __restrict__ b2,
                           float* __restrict__ out, float invN) {
  __shared__ float p[64], h[64];
  const int tid = threadIdx.x;
  if (tid < 64) p[tid] = pool[tid] * invN;
  __syncthreads();
  if (tid < 64) {
    float s = b1[tid];
    for (int k = 0; k < 64; k++) s = fmaf(p[k], W1[k * 64 + tid], s);
    h[tid] = fmaxf(s, 0.f);
  }
  __syncthreads();
  float s = b2[tid];
  for (int k = 0; k < 64; k++) s = fmaf(h[k], W2[k * 128 + tid], s);
  out[tid] = s;
}

extern "C" void kernel_launch(void* const* d_in, const int* in_sizes, int n_in,
                              void* d_out, int out_size, void* d_ws,
                              size_t ws_size, hipStream_t stream) {
  const int*   an  = (const int*)d_in[0];
  // d_in[1] positions, d_in[2] lattice: unused (matches reference)
  const int*   ei  = (const int*)d_in[3];
  const float* emb = (const float*)d_in[4];
  const float* Wl  = (const float*)d_in[5];
  const float* bl  = (const float*)d_in[6];
  const float* Wg  = (const float*)d_in[7];
  const float* bg  = (const float*)d_in[8];
  const float* W1  = (const float*)d_in[9];
  const float* b1  = (const float*)d_in[10];
  const float* W2  = (const float*)d_in[11];
  const float* b2  = (const float*)d_in[12];
  float* out = (float*)d_out;

  const int N = in_sizes[0];
  const int E = in_sizes[3] / 2;
  const int* row = ei;
  const int* col = ei + E;

  const size_t NB = (size_t)N * H * sizeof(float);
  char* ws = (char*)d_ws;
  float* x    = (float*)(ws);
  float* lin  = (float*)(ws + NB);
  float* agg  = (float*)(ws + 2 * NB);
  float* pool = (float*)(ws + 3 * NB);
  // requires ws_size >= 3*NB + 256 bytes (~77 MB)

  embed_kernel<<<2048, 256, 0, stream>>>(an, emb, x, N);

  for (int l = 0; l < 3; l++) {
    lin_kernel<<<1024, 256, 0, stream>>>(x, Wl + l * H * H, bl + l * H, lin, N);
    hipMemsetAsync(agg, 0, NB, stream);
    edge_kernel<<<512, 256, 0, stream>>>(x, lin, row, col, Wg + l * 2 * H * H,
                                         bg + l * H, agg, E);
    update_kernel<<<2048, 256, 0, stream>>>(agg, lin, x, N * H / 4);
  }

  hipMemsetAsync(pool, 0, 64 * sizeof(float), stream);
  pool_kernel<<<1024, 256, 0, stream>>>(x, pool, N);
  mlp_kernel<<<1, 128, 0, stream>>>(pool, W1, b1, W2, b2, out, 1.0f / (float)N);
}

// Round 3
// 854.019 us; speedup vs baseline: 3.4208x; 3.4208x over previous
//
#include <hip/hip_runtime.h>
#include <hip/hip_bf16.h>
#include <stdint.h>

// CrystalGraphEncoder on MI355X — round 2 (resubmit): algebraic gate split + CSR.
//
// gate = sigmoid([x_r‖x_c]@Wg+bg) = sigmoid((x@Wg_top)[r] + (x@Wg_bot+bg)[c])
// => per-node precompute gr,gc,lin; per-edge work becomes 3 gathers + 6 flops.
// Edges are layer-invariant => build CSR (sort-by-row) ONCE, aggregate with one
// wave per atom (lane=channel), no atomics, fused with relu node-update.
//
// ws: x | lin | gr | gc | hist | offs | offs_work | cols | pool  (~108 MB)

#define H 64
#define TE 64

__device__ __forceinline__ void fma4(float4& acc, const float4 a,
                                     const float4 w0, const float4 w1,
                                     const float4 w2, const float4 w3) {
  acc.x = fmaf(a.x, w0.x, acc.x); acc.y = fmaf(a.x, w0.y, acc.y);
  acc.z = fmaf(a.x, w0.z, acc.z); acc.w = fmaf(a.x, w0.w, acc.w);
  acc.x = fmaf(a.y, w1.x, acc.x); acc.y = fmaf(a.y, w1.y, acc.y);
  acc.z = fmaf(a.y, w1.z, acc.z); acc.w = fmaf(a.y, w1.w, acc.w);
  acc.x = fmaf(a.z, w2.x, acc.x); acc.y = fmaf(a.z, w2.y, acc.y);
  acc.z = fmaf(a.z, w2.z, acc.z); acc.w = fmaf(a.z, w2.w, acc.w);
  acc.x = fmaf(a.w, w3.x, acc.x); acc.y = fmaf(a.w, w3.y, acc.y);
  acc.z = fmaf(a.w, w3.z, acc.z); acc.w = fmaf(a.w, w3.w, acc.w);
}

__device__ __forceinline__ float sigmoidf_fast(float z) {
  // 1/(1+e^-z); v_exp_f32 + v_rcp_f32
  return __builtin_amdgcn_rcpf(1.f + __expf(-z));
}

// ---------- embed: x[i][c] = emb[an[i]][c] ----------
__global__ void embed_kernel(const int* __restrict__ an,
                             const float* __restrict__ emb,
                             float* __restrict__ x, int N) {
  const int total = N * (H / 4);
  for (int t = blockIdx.x * blockDim.x + threadIdx.x; t < total;
       t += gridDim.x * blockDim.x) {
    const int i = t >> 4, c4 = t & 15;
    ((float4*)x)[t] = ((const float4*)emb)[an[i] * 16 + c4];
  }
}

// ---------- CSR build (once per launch; edges layer-invariant) ----------
__global__ void hist_kernel(const int* __restrict__ row, int* __restrict__ hist,
                            int E) {
  for (int e = blockIdx.x * blockDim.x + threadIdx.x; e < E;
       e += gridDim.x * blockDim.x)
    atomicAdd(&hist[row[e]], 1);
}

// single block, 1024 threads: exclusive scan of hist[N] -> offs, offs_work
__global__ void scan_kernel(const int* __restrict__ hist, int* __restrict__ offs,
                            int* __restrict__ offs_work, int N, int E) {
  __shared__ int sums[1024];
  const int tid = threadIdx.x;
  const int chunk = (N + 1023) / 1024;
  const int start = tid * chunk, end = min(start + chunk, N);
  int s = 0;
  for (int j = start; j < end; j++) s += hist[j];
  sums[tid] = s;
  __syncthreads();
  for (int off = 1; off < 1024; off <<= 1) {  // Hillis-Steele inclusive
    int v = 0;
    if (tid >= off) v = sums[tid - off];
    __syncthreads();
    sums[tid] += v;
    __syncthreads();
  }
  int run = sums[tid] - s;  // exclusive prefix of this chunk
  for (int j = start; j < end; j++) {
    const int h = hist[j];
    offs[j] = run;
    offs_work[j] = run;
    run += h;
  }
  if (tid == 0) offs[N] = E;
}

__global__ void scatter_kernel(const int* __restrict__ row,
                               const int* __restrict__ col,
                               int* __restrict__ offs_work,
                               int* __restrict__ cols, int E) {
  for (int e = blockIdx.x * blockDim.x + threadIdx.x; e < E;
       e += gridDim.x * blockDim.x) {
    const int pos = atomicAdd(&offs_work[row[e]], 1);
    cols[pos] = col[e];
  }
}

// ---------- fused node matmuls: lin = x@Wl+bl, gr = x@Wgr, gc = x@Wgc+bg ----------
__global__ __launch_bounds__(256, 2) void node_mm3_kernel(
    const float* __restrict__ x, const float* __restrict__ Wl,
    const float* __restrict__ bl, const float* __restrict__ Wgr,
    const float* __restrict__ Wgc, const float* __restrict__ bg,
    float* __restrict__ lin, float* __restrict__ gr, float* __restrict__ gc,
    int N) {
  __shared__ __align__(16) float xt[TE][68];
  __shared__ __align__(16) float Wls[H][H], Wgrs[H][H], Wgcs[H][H];
  const int tid = threadIdx.x;
  const int lane = tid & 63, wid = tid >> 6;
  for (int idx = tid; idx < H * H; idx += 256) {
    const int r = idx >> 6, c = idx & 63;
    Wls[r][c] = Wl[idx];
    Wgrs[r][c] = Wgr[idx];
    Wgcs[r][c] = Wgc[idx];
  }
  const int jb = (tid & 15) * 4, eb = (tid >> 4) * 4;
  const float4 blv = *(const float4*)(bl + jb);
  const float4 bgv = *(const float4*)(bg + jb);
  const float4 z4 = make_float4(0.f, 0.f, 0.f, 0.f);

  for (int base = blockIdx.x * TE; base < N; base += gridDim.x * TE) {
    const int ne = min(TE, N - base);
    __syncthreads();
    for (int e = wid; e < ne; e += 4) xt[e][lane] = x[(base + e) * H + lane];
    __syncthreads();
    float4 al0 = blv, al1 = blv, al2 = blv, al3 = blv;
    float4 ar0 = z4, ar1 = z4, ar2 = z4, ar3 = z4;
    float4 ac0 = bgv, ac1 = bgv, ac2 = bgv, ac3 = bgv;
#pragma unroll 4
    for (int k = 0; k < H; k += 4) {
      const float4 v0 = *(const float4*)&xt[eb + 0][k];
      const float4 v1 = *(const float4*)&xt[eb + 1][k];
      const float4 v2 = *(const float4*)&xt[eb + 2][k];
      const float4 v3 = *(const float4*)&xt[eb + 3][k];
      {
        const float4 w0 = *(const float4*)&Wls[k + 0][jb];
        const float4 w1 = *(const float4*)&Wls[k + 1][jb];
        const float4 w2 = *(const float4*)&Wls[k + 2][jb];
        const float4 w3 = *(const float4*)&Wls[k + 3][jb];
        fma4(al0, v0, w0, w1, w2, w3); fma4(al1, v1, w0, w1, w2, w3);
        fma4(al2, v2, w0, w1, w2, w3); fma4(al3, v3, w0, w1, w2, w3);
      }
      {
        const float4 w0 = *(const float4*)&Wgrs[k + 0][jb];
        const float4 w1 = *(const float4*)&Wgrs[k + 1][jb];
        const float4 w2 = *(const float4*)&Wgrs[k + 2][jb];
        const float4 w3 = *(const float4*)&Wgrs[k + 3][jb];
        fma4(ar0, v0, w0, w1, w2, w3); fma4(ar1, v1, w0, w1, w2, w3);
        fma4(ar2, v2, w0, w1, w2, w3); fma4(ar3, v3, w0, w1, w2, w3);
      }
      {
        const float4 w0 = *(const float4*)&Wgcs[k + 0][jb];
        const float4 w1 = *(const float4*)&Wgcs[k + 1][jb];
        const float4 w2 = *(const float4*)&Wgcs[k + 2][jb];
        const float4 w3 = *(const float4*)&Wgcs[k + 3][jb];
        fma4(ac0, v0, w0, w1, w2, w3); fma4(ac1, v1, w0, w1, w2, w3);
        fma4(ac2, v2, w0, w1, w2, w3); fma4(ac3, v3, w0, w1, w2, w3);
      }
    }
#pragma unroll
    for (int i = 0; i < 4; i++) {
      const int e = eb + i;
      if (e < ne) {
        const size_t o = (size_t)(base + e) * H + jb;
        *(float4*)&lin[o] = (i == 0) ? al0 : (i == 1) ? al1 : (i == 2) ? al2 : al3;
        *(float4*)&gr[o]  = (i == 0) ? ar0 : (i == 1) ? ar1 : (i == 2) ? ar2 : ar3;
        *(float4*)&gc[o]  = (i == 0) ? ac0 : (i == 1) ? ac1 : (i == 2) ? ac2 : ac3;
      }
    }
  }
}

// ---------- aggregate + update: one wave per atom, lane = channel ----------
// x[i] = relu( sum_{c in nbrs(i)} sigmoid(gr[i]+gc[c]) * lin[c]  + lin[i] )
__global__ __launch_bounds__(256) void agg_kernel(
    const float* __restrict__ gr, const float* __restrict__ gc,
    const float* __restrict__ lin, const int* __restrict__ offs,
    const int* __restrict__ cols, float* __restrict__ x, int N) {
  const int lane = threadIdx.x & 63, w = threadIdx.x >> 6;
  for (int i = blockIdx.x * 4 + w; i < N; i += gridDim.x * 4) {
    const int s = offs[i], e = offs[i + 1];
    const float gri = gr[(size_t)i * H + lane];
    float acc = 0.f;
    int t = s;
    for (; t + 1 < e; t += 2) {  // 2-deep to overlap gather latency
      const int c0 = cols[t], c1 = cols[t + 1];
      const float g0 = gc[(size_t)c0 * H + lane];
      const float l0 = lin[(size_t)c0 * H + lane];
      const float g1 = gc[(size_t)c1 * H + lane];
      const float l1 = lin[(size_t)c1 * H + lane];
      acc += l0 * sigmoidf_fast(gri + g0);
      acc += l1 * sigmoidf_fast(gri + g1);
    }
    if (t < e) {
      const int c0 = cols[t];
      const float g0 = gc[(size_t)c0 * H + lane];
      const float l0 = lin[(size_t)c0 * H + lane];
      acc += l0 * sigmoidf_fast(gri + g0);
    }
    const float li = lin[(size_t)i * H + lane];
    x[(size_t)i * H + lane] = fmaxf(acc + li, 0.f);
  }
}

// ---------- mean pool ----------
__global__ void pool_kernel(const float* __restrict__ x,
                            float* __restrict__ pool, int N) {
  __shared__ float ps[4][64];
  const int tid = threadIdx.x, c = tid & 63, wid = tid >> 6;
  float s = 0.f;
  for (int i = blockIdx.x * 4 + wid; i < N; i += gridDim.x * 4)
    s += x[(size_t)i * H + c];
  ps[wid][c] = s;
  __syncthreads();
  if (tid < 64) {
    const float t = ps[0][tid] + ps[1][tid] + ps[2][tid] + ps[3][tid];
    atomicAdd(&pool[tid], t);
  }
}

// ---------- final MLP ----------
__global__ void mlp_kernel(const float* __restrict__ pool,
                           const float* __restrict__ W1,
                           const float* __restrict__ b1,
                           const float* __restrict__ W2,
                           const float* __restrict__ b2,
                           float* __restrict__ out, float invN) {
  __shared__ float p[64], h[64];
  const int tid = threadIdx.x;
  if (tid < 64) p[tid] = pool[tid] * invN;
  __syncthreads();
  if (tid < 64) {
    float s = b1[tid];
    for (int k = 0; k < 64; k++) s = fmaf(p[k], W1[k * 64 + tid], s);
    h[tid] = fmaxf(s, 0.f);
  }
  __syncthreads();
  float s = b2[tid];
  for (int k = 0; k < 64; k++) s = fmaf(h[k], W2[k * 128 + tid], s);
  out[tid] = s;
}

extern "C" void kernel_launch(void* const* d_in, const int* in_sizes, int n_in,
                              void* d_out, int out_size, void* d_ws,
                              size_t ws_size, hipStream_t stream) {
  const int*   an  = (const int*)d_in[0];
  const int*   ei  = (const int*)d_in[3];
  const float* emb = (const float*)d_in[4];
  const float* Wl  = (const float*)d_in[5];
  const float* bl  = (const float*)d_in[6];
  const float* Wg  = (const float*)d_in[7];
  const float* bg  = (const float*)d_in[8];
  const float* W1  = (const float*)d_in[9];
  const float* b1  = (const float*)d_in[10];
  const float* W2  = (const float*)d_in[11];
  const float* b2  = (const float*)d_in[12];
  float* out = (float*)d_out;

  const int N = in_sizes[0];
  const int E = in_sizes[3] / 2;
  const int* row = ei;
  const int* col = ei + E;

  const size_t NB = (size_t)N * H * sizeof(float);
  char* ws = (char*)d_ws;
  float* x    = (float*)(ws);
  float* lin  = (float*)(ws + NB);
  float* gr   = (float*)(ws + 2 * NB);
  float* gc   = (float*)(ws + 3 * NB);
  char*  p    = ws + 4 * NB;
  int* hist      = (int*)p;            p += ((size_t)N + 1) * 4;
  int* offs      = (int*)p;            p += ((size_t)N + 1) * 4;
  int* offs_work = (int*)p;            p += ((size_t)N + 1) * 4;
  int* cols      = (int*)p;            p += (size_t)E * 4;
  float* pool    = (float*)p;
  // total ~ 4*25.6MB + 1.2MB + 4MB + 256B  ≈ 108 MB

  embed_kernel<<<2048, 256, 0, stream>>>(an, emb, x, N);

  // CSR build (edges are the same every layer)
  hipMemsetAsync(hist, 0, (size_t)N * 4, stream);
  hist_kernel<<<2048, 256, 0, stream>>>(row, hist, E);
  scan_kernel<<<1, 1024, 0, stream>>>(hist, offs, offs_work, N, E);
  scatter_kernel<<<2048, 256, 0, stream>>>(row, col, offs_work, cols, E);

  const int aggGrid = (N + 3) / 4;
  for (int l = 0; l < 3; l++) {
    node_mm3_kernel<<<512, 256, 0, stream>>>(
        x, Wl + l * H * H, bl + l * H, Wg + l * 2 * H * H,
        Wg + l * 2 * H * H + H * H, bg + l * H, lin, gr, gc, N);
    agg_kernel<<<aggGrid, 256, 0, stream>>>(gr, gc, lin, offs, cols, x, N);
  }

  hipMemsetAsync(pool, 0, 64 * sizeof(float), stream);
  pool_kernel<<<1024, 256, 0, stream>>>(x, pool, N);
  mlp_kernel<<<1, 128, 0, stream>>>(pool, W1, b1, W2, b2, out, 1.0f / (float)N);
}

// Round 4
// 505.317 us; speedup vs baseline: 5.7814x; 1.6901x over previous
//
#include <hip/hip_runtime.h>
#include <hip/hip_bf16.h>
#include <stdint.h>

// CrystalGraphEncoder on MI355X — round 4:
//  R3 post-mortem: single-block scan was 234us (27%); agg gathers ~140us/layer.
//  Fix 1: hierarchical 3-kernel scan (~15us).
//  Fix 2: pack (bf16(gc), bf16(lin)) into one u32/channel -> one 256B gather
//         per edge (4x fewer gather bytes), cols batch-loaded + shfl-broadcast.
//
// ws: x | lin | gr | glpk | hist | offs | offs_work | cols | pool  (~108 MB)

#define H 64
#define TE 64
#define SCAN_BS 256
#define SCAN_ELEMS 1024  // per block: 256 threads x 4

__device__ __forceinline__ void fma4(float4& acc, const float4 a,
                                     const float4 w0, const float4 w1,
                                     const float4 w2, const float4 w3) {
  acc.x = fmaf(a.x, w0.x, acc.x); acc.y = fmaf(a.x, w0.y, acc.y);
  acc.z = fmaf(a.x, w0.z, acc.z); acc.w = fmaf(a.x, w0.w, acc.w);
  acc.x = fmaf(a.y, w1.x, acc.x); acc.y = fmaf(a.y, w1.y, acc.y);
  acc.z = fmaf(a.y, w1.z, acc.z); acc.w = fmaf(a.y, w1.w, acc.w);
  acc.x = fmaf(a.z, w2.x, acc.x); acc.y = fmaf(a.z, w2.y, acc.y);
  acc.z = fmaf(a.z, w2.z, acc.z); acc.w = fmaf(a.z, w2.w, acc.w);
  acc.x = fmaf(a.w, w3.x, acc.x); acc.y = fmaf(a.w, w3.y, acc.y);
  acc.z = fmaf(a.w, w3.z, acc.z); acc.w = fmaf(a.w, w3.w, acc.w);
}

__device__ __forceinline__ float sigmoidf_fast(float z) {
  return __builtin_amdgcn_rcpf(1.f + __expf(-z));
}

// pack: hi16 = bf16(lin), lo16 = bf16(gc), both RNE
__device__ __forceinline__ uint32_t pack_gl(float gc, float lin) {
  uint32_t ug = __float_as_uint(gc);
  ug = (ug + 0x7fffu + ((ug >> 16) & 1u)) >> 16;
  uint32_t ul = __float_as_uint(lin);
  ul = ((ul + 0x7fffu + ((ul >> 16) & 1u)) >> 16) << 16;
  return ul | ug;
}
__device__ __forceinline__ float unpack_gc(uint32_t p) {
  return __uint_as_float(p << 16);
}
__device__ __forceinline__ float unpack_lin(uint32_t p) {
  return __uint_as_float(p & 0xffff0000u);
}

// ---------- embed ----------
__global__ void embed_kernel(const int* __restrict__ an,
                             const float* __restrict__ emb,
                             float* __restrict__ x, int N) {
  const int total = N * (H / 4);
  for (int t = blockIdx.x * blockDim.x + threadIdx.x; t < total;
       t += gridDim.x * blockDim.x) {
    const int i = t >> 4, c4 = t & 15;
    ((float4*)x)[t] = ((const float4*)emb)[an[i] * 16 + c4];
  }
}

// ---------- CSR build ----------
__global__ void hist_kernel(const int* __restrict__ row, int* __restrict__ hist,
                            int E) {
  for (int e = blockIdx.x * blockDim.x + threadIdx.x; e < E;
       e += gridDim.x * blockDim.x)
    atomicAdd(&hist[row[e]], 1);
}

// k1: per-block sums of 1024-elem chunks
__global__ __launch_bounds__(SCAN_BS) void scan_partial_kernel(
    const int* __restrict__ hist, int* __restrict__ bsum, int N) {
  __shared__ int red[SCAN_BS];
  const int tid = threadIdx.x;
  const int base = blockIdx.x * SCAN_ELEMS + tid * 4;
  int s = 0;
  if (base + 3 < N) {
    const int4 v = *(const int4*)(hist + base);
    s = v.x + v.y + v.z + v.w;
  } else {
    for (int j = 0; j < 4; j++) if (base + j < N) s += hist[base + j];
  }
  red[tid] = s;
  __syncthreads();
  for (int off = SCAN_BS / 2; off > 0; off >>= 1) {
    if (tid < off) red[tid] += red[tid + off];
    __syncthreads();
  }
  if (tid == 0) bsum[blockIdx.x] = red[0];
}

// k2: single block exclusive scan of block sums (nb <= 1024)
__global__ __launch_bounds__(1024) void scan_bsum_kernel(
    const int* __restrict__ bsum, int* __restrict__ boff, int nb) {
  __shared__ int sh[1024];
  const int tid = threadIdx.x;
  const int mine = (tid < nb) ? bsum[tid] : 0;
  sh[tid] = mine;
  __syncthreads();
  for (int off = 1; off < 1024; off <<= 1) {
    const int v = (tid >= off) ? sh[tid - off] : 0;
    __syncthreads();
    sh[tid] += v;
    __syncthreads();
  }
  if (tid < nb) boff[tid] = sh[tid] - mine;  // exclusive
}

// k3: local scan + apply block offset, write offs & offs_work
__global__ __launch_bounds__(SCAN_BS) void scan_apply_kernel(
    const int* __restrict__ hist, const int* __restrict__ boff,
    int* __restrict__ offs, int* __restrict__ offs_work, int N, int E) {
  __shared__ int red[SCAN_BS];
  const int tid = threadIdx.x;
  const int base = blockIdx.x * SCAN_ELEMS + tid * 4;
  int v0 = 0, v1 = 0, v2 = 0, v3 = 0;
  if (base + 3 < N) {
    const int4 v = *(const int4*)(hist + base);
    v0 = v.x; v1 = v.y; v2 = v.z; v3 = v.w;
  } else {
    if (base < N)     v0 = hist[base];
    if (base + 1 < N) v1 = hist[base + 1];
    if (base + 2 < N) v2 = hist[base + 2];
    if (base + 3 < N) v3 = hist[base + 3];
  }
  const int s = v0 + v1 + v2 + v3;
  red[tid] = s;
  __syncthreads();
  for (int off = 1; off < SCAN_BS; off <<= 1) {
    const int v = (tid >= off) ? red[tid - off] : 0;
    __syncthreads();
    red[tid] += v;
    __syncthreads();
  }
  int run = boff[blockIdx.x] + red[tid] - s;  // exclusive prefix
  if (base < N)     { offs[base] = run;     offs_work[base] = run;     run += v0; }
  if (base + 1 < N) { offs[base + 1] = run; offs_work[base + 1] = run; run += v1; }
  if (base + 2 < N) { offs[base + 2] = run; offs_work[base + 2] = run; run += v2; }
  if (base + 3 < N) { offs[base + 3] = run; offs_work[base + 3] = run; run += v3; }
  if (blockIdx.x == 0 && tid == 0) offs[N] = E;
}

__global__ void scatter_kernel(const int* __restrict__ row,
                               const int* __restrict__ col,
                               int* __restrict__ offs_work,
                               int* __restrict__ cols, int E) {
  for (int e = blockIdx.x * blockDim.x + threadIdx.x; e < E;
       e += gridDim.x * blockDim.x) {
    const int pos = atomicAdd(&offs_work[row[e]], 1);
    cols[pos] = col[e];
  }
}

// ---------- node matmuls: lin=x@Wl+bl (f32), gr=x@Wgr (f32),
//            glpk = pack(bf16(x@Wgc+bg), bf16(lin)) ----------
__global__ __launch_bounds__(256, 2) void node_mm3_kernel(
    const float* __restrict__ x, const float* __restrict__ Wl,
    const float* __restrict__ bl, const float* __restrict__ Wgr,
    const float* __restrict__ Wgc, const float* __restrict__ bg,
    float* __restrict__ lin, float* __restrict__ gr,
    uint32_t* __restrict__ glpk, int N) {
  __shared__ __align__(16) float xt[TE][68];
  __shared__ __align__(16) float Wls[H][H], Wgrs[H][H], Wgcs[H][H];
  const int tid = threadIdx.x;
  const int lane = tid & 63, wid = tid >> 6;
  for (int idx = tid; idx < H * H; idx += 256) {
    const int r = idx >> 6, c = idx & 63;
    Wls[r][c] = Wl[idx];
    Wgrs[r][c] = Wgr[idx];
    Wgcs[r][c] = Wgc[idx];
  }
  const int jb = (tid & 15) * 4, eb = (tid >> 4) * 4;
  const float4 blv = *(const float4*)(bl + jb);
  const float4 bgv = *(const float4*)(bg + jb);
  const float4 z4 = make_float4(0.f, 0.f, 0.f, 0.f);

  for (int base = blockIdx.x * TE; base < N; base += gridDim.x * TE) {
    const int ne = min(TE, N - base);
    __syncthreads();
    for (int e = wid; e < ne; e += 4) xt[e][lane] = x[(size_t)(base + e) * H + lane];
    __syncthreads();
    float4 al0 = blv, al1 = blv, al2 = blv, al3 = blv;
    float4 ar0 = z4, ar1 = z4, ar2 = z4, ar3 = z4;
    float4 ac0 = bgv, ac1 = bgv, ac2 = bgv, ac3 = bgv;
#pragma unroll 4
    for (int k = 0; k < H; k += 4) {
      const float4 v0 = *(const float4*)&xt[eb + 0][k];
      const float4 v1 = *(const float4*)&xt[eb + 1][k];
      const float4 v2 = *(const float4*)&xt[eb + 2][k];
      const float4 v3 = *(const float4*)&xt[eb + 3][k];
      {
        const float4 w0 = *(const float4*)&Wls[k + 0][jb];
        const float4 w1 = *(const float4*)&Wls[k + 1][jb];
        const float4 w2 = *(const float4*)&Wls[k + 2][jb];
        const float4 w3 = *(const float4*)&Wls[k + 3][jb];
        fma4(al0, v0, w0, w1, w2, w3); fma4(al1, v1, w0, w1, w2, w3);
        fma4(al2, v2, w0, w1, w2, w3); fma4(al3, v3, w0, w1, w2, w3);
      }
      {
        const float4 w0 = *(const float4*)&Wgrs[k + 0][jb];
        const float4 w1 = *(const float4*)&Wgrs[k + 1][jb];
        const float4 w2 = *(const float4*)&Wgrs[k + 2][jb];
        const float4 w3 = *(const float4*)&Wgrs[k + 3][jb];
        fma4(ar0, v0, w0, w1, w2, w3); fma4(ar1, v1, w0, w1, w2, w3);
        fma4(ar2, v2, w0, w1, w2, w3); fma4(ar3, v3, w0, w1, w2, w3);
      }
      {
        const float4 w0 = *(const float4*)&Wgcs[k + 0][jb];
        const float4 w1 = *(const float4*)&Wgcs[k + 1][jb];
        const float4 w2 = *(const float4*)&Wgcs[k + 2][jb];
        const float4 w3 = *(const float4*)&Wgcs[k + 3][jb];
        fma4(ac0, v0, w0, w1, w2, w3); fma4(ac1, v1, w0, w1, w2, w3);
        fma4(ac2, v2, w0, w1, w2, w3); fma4(ac3, v3, w0, w1, w2, w3);
      }
    }
#pragma unroll
    for (int i = 0; i < 4; i++) {
      const int e = eb + i;
      if (e < ne) {
        const size_t o = (size_t)(base + e) * H + jb;
        const float4 al = (i == 0) ? al0 : (i == 1) ? al1 : (i == 2) ? al2 : al3;
        const float4 ar = (i == 0) ? ar0 : (i == 1) ? ar1 : (i == 2) ? ar2 : ar3;
        const float4 ac = (i == 0) ? ac0 : (i == 1) ? ac1 : (i == 2) ? ac2 : ac3;
        *(float4*)&lin[o] = al;
        *(float4*)&gr[o] = ar;
        uint4 pk;
        pk.x = pack_gl(ac.x, al.x);
        pk.y = pack_gl(ac.y, al.y);
        pk.z = pack_gl(ac.z, al.z);
        pk.w = pack_gl(ac.w, al.w);
        *(uint4*)&glpk[o] = pk;
      }
    }
  }
}

// ---------- aggregate + update: one wave per atom, lane = channel ----------
// x[i] = relu( sum_c sigmoid(gr[i]+gc[c]) * lin[c] + lin[i] ), gc/lin from glpk
__global__ __launch_bounds__(256) void agg_kernel(
    const float* __restrict__ gr, const uint32_t* __restrict__ glpk,
    const float* __restrict__ lin, const int* __restrict__ offs,
    const int* __restrict__ cols, float* __restrict__ x, int N) {
  const int lane = threadIdx.x & 63, w = threadIdx.x >> 6;
  for (int i = blockIdx.x * 4 + w; i < N; i += gridDim.x * 4) {
    const int s = offs[i], e = offs[i + 1];
    const float gri = gr[(size_t)i * H + lane];
    float acc = 0.f;
    for (int cb = s; cb < e; cb += 64) {
      const int nchunk = min(64, e - cb);
      const int myc = (lane < nchunk) ? cols[cb + lane] : 0;
      int j = 0;
      for (; j + 3 < nchunk; j += 4) {
        const int c0 = __shfl(myc, j + 0), c1 = __shfl(myc, j + 1);
        const int c2 = __shfl(myc, j + 2), c3 = __shfl(myc, j + 3);
        const uint32_t p0 = glpk[(size_t)c0 * H + lane];
        const uint32_t p1 = glpk[(size_t)c1 * H + lane];
        const uint32_t p2 = glpk[(size_t)c2 * H + lane];
        const uint32_t p3 = glpk[(size_t)c3 * H + lane];
        acc += unpack_lin(p0) * sigmoidf_fast(gri + unpack_gc(p0));
        acc += unpack_lin(p1) * sigmoidf_fast(gri + unpack_gc(p1));
        acc += unpack_lin(p2) * sigmoidf_fast(gri + unpack_gc(p2));
        acc += unpack_lin(p3) * sigmoidf_fast(gri + unpack_gc(p3));
      }
      for (; j < nchunk; j++) {
        const int c0 = __shfl(myc, j);
        const uint32_t p0 = glpk[(size_t)c0 * H + lane];
        acc += unpack_lin(p0) * sigmoidf_fast(gri + unpack_gc(p0));
      }
    }
    const float li = lin[(size_t)i * H + lane];
    x[(size_t)i * H + lane] = fmaxf(acc + li, 0.f);
  }
}

// ---------- mean pool ----------
__global__ void pool_kernel(const float* __restrict__ x,
                            float* __restrict__ pool, int N) {
  __shared__ float ps[4][64];
  const int tid = threadIdx.x, c = tid & 63, wid = tid >> 6;
  float s = 0.f;
  for (int i = blockIdx.x * 4 + wid; i < N; i += gridDim.x * 4)
    s += x[(size_t)i * H + c];
  ps[wid][c] = s;
  __syncthreads();
  if (tid < 64) {
    const float t = ps[0][tid] + ps[1][tid] + ps[2][tid] + ps[3][tid];
    atomicAdd(&pool[tid], t);
  }
}

// ---------- final MLP ----------
__global__ void mlp_kernel(const float* __restrict__ pool,
                           const float* __restrict__ W1,
                           const float* __restrict__ b1,
                           const float* __restrict__ W2,
                           const float* __restrict__ b2,
                           float* __restrict__ out, float invN) {
  __shared__ float p[64], h[64];
  const int tid = threadIdx.x;
  if (tid < 64) p[tid] = pool[tid] * invN;
  __syncthreads();
  if (tid < 64) {
    float s = b1[tid];
    for (int k = 0; k < 64; k++) s = fmaf(p[k], W1[k * 64 + tid], s);
    h[tid] = fmaxf(s, 0.f);
  }
  __syncthreads();
  float s = b2[tid];
  for (int k = 0; k < 64; k++) s = fmaf(h[k], W2[k * 128 + tid], s);
  out[tid] = s;
}

extern "C" void kernel_launch(void* const* d_in, const int* in_sizes, int n_in,
                              void* d_out, int out_size, void* d_ws,
                              size_t ws_size, hipStream_t stream) {
  const int*   an  = (const int*)d_in[0];
  const int*   ei  = (const int*)d_in[3];
  const float* emb = (const float*)d_in[4];
  const float* Wl  = (const float*)d_in[5];
  const float* bl  = (const float*)d_in[6];
  const float* Wg  = (const float*)d_in[7];
  const float* bg  = (const float*)d_in[8];
  const float* W1  = (const float*)d_in[9];
  const float* b1  = (const float*)d_in[10];
  const float* W2  = (const float*)d_in[11];
  const float* b2  = (const float*)d_in[12];
  float* out = (float*)d_out;

  const int N = in_sizes[0];
  const int E = in_sizes[3] / 2;
  const int* row = ei;
  const int* col = ei + E;

  const size_t NB = (size_t)N * H * sizeof(float);
  char* ws = (char*)d_ws;
  float*    x    = (float*)(ws);
  float*    lin  = (float*)(ws + NB);
  float*    gr   = (float*)(ws + 2 * NB);
  uint32_t* glpk = (uint32_t*)(ws + 3 * NB);
  char* p = ws + 4 * NB;
  int* hist      = (int*)p;  p += ((size_t)N + 1) * 4;
  int* offs      = (int*)p;  p += ((size_t)N + 1) * 4;
  int* offs_work = (int*)p;  p += ((size_t)N + 1) * 4;
  int* cols      = (int*)p;  p += (size_t)E * 4;
  int* bsum      = (int*)p;  p += 4096;
  int* boff      = (int*)p;  p += 4096;
  float* pool    = (float*)p;
  // total ≈ 4*25.6MB + 1.2MB + 4MB + 32KB ≈ 108 MB

  embed_kernel<<<2048, 256, 0, stream>>>(an, emb, x, N);

  // CSR build (edges identical every layer)
  const int nb = (N + SCAN_ELEMS - 1) / SCAN_ELEMS;  // 98 for N=100K (<=1024)
  hipMemsetAsync(hist, 0, (size_t)N * 4, stream);
  hist_kernel<<<2048, 256, 0, stream>>>(row, hist, E);
  scan_partial_kernel<<<nb, SCAN_BS, 0, stream>>>(hist, bsum, N);
  scan_bsum_kernel<<<1, 1024, 0, stream>>>(bsum, boff, nb);
  scan_apply_kernel<<<nb, SCAN_BS, 0, stream>>>(hist, boff, offs, offs_work, N, E);
  scatter_kernel<<<2048, 256, 0, stream>>>(row, col, offs_work, cols, E);

  const int aggGrid = (N + 3) / 4;
  for (int l = 0; l < 3; l++) {
    node_mm3_kernel<<<512, 256, 0, stream>>>(
        x, Wl + l * H * H, bl + l * H, Wg + l * 2 * H * H,
        Wg + l * 2 * H * H + H * H, bg + l * H, lin, gr, glpk, N);
    agg_kernel<<<aggGrid, 256, 0, stream>>>(gr, glpk, lin, offs, cols, x, N);
  }

  hipMemsetAsync(pool, 0, 64 * sizeof(float), stream);
  pool_kernel<<<1024, 256, 0, stream>>>(x, pool, N);
  mlp_kernel<<<1, 128, 0, stream>>>(pool, W1, b1, W2, b2, out, 1.0f / (float)N);
}

// Round 5
// 445.084 us; speedup vs baseline: 6.5638x; 1.1353x over previous
//
#include <hip/hip_runtime.h>
#include <hip/hip_bf16.h>
#include <stdint.h>

// CrystalGraphEncoder on MI355X — round 5:
//  - x kept in bf16 end-to-end
//  - node_mm3 via mfma_f32_16x16x32_bf16 (A from global bf16 x; embed fused
//    into layer-0 A-load; B-frags from L2-resident W)
//  - lin f32 array dropped (self-term from packed glpk bf16)
//  - CSR build unchanged (scatter is next round's target)
//
// ws: x_bf16 | gr f32 | glpk u32 | hist | offs | offs_work | cols | bsum | boff | pool  (~69 MB)

#define H 64
#define SCAN_BS 256
#define SCAN_ELEMS 1024

typedef __attribute__((ext_vector_type(8))) short bf16x8;
typedef __attribute__((ext_vector_type(4))) float f32x4;

__device__ __forceinline__ float sigmoidf_fast(float z) {
  return __builtin_amdgcn_rcpf(1.f + __expf(-z));
}

__device__ __forceinline__ ushort f2bf(float f) {  // RNE
  uint32_t u = __float_as_uint(f);
  u = (u + 0x7fffu + ((u >> 16) & 1u)) >> 16;
  return (ushort)u;
}
// pack: hi16 = bf16(lin), lo16 = bf16(gc)
__device__ __forceinline__ uint32_t pack_gl(float gc, float lin) {
  uint32_t ug = __float_as_uint(gc);
  ug = (ug + 0x7fffu + ((ug >> 16) & 1u)) >> 16;
  uint32_t ul = __float_as_uint(lin);
  ul = ((ul + 0x7fffu + ((ul >> 16) & 1u)) >> 16) << 16;
  return ul | ug;
}
__device__ __forceinline__ float unpack_gc(uint32_t p) {
  return __uint_as_float(p << 16);
}
__device__ __forceinline__ float unpack_lin(uint32_t p) {
  return __uint_as_float(p & 0xffff0000u);
}

// ---------- CSR build ----------
__global__ void hist_kernel(const int* __restrict__ row, int* __restrict__ hist,
                            int E) {
  for (int e = blockIdx.x * blockDim.x + threadIdx.x; e < E;
       e += gridDim.x * blockDim.x)
    atomicAdd(&hist[row[e]], 1);
}

__global__ __launch_bounds__(SCAN_BS) void scan_partial_kernel(
    const int* __restrict__ hist, int* __restrict__ bsum, int N) {
  __shared__ int red[SCAN_BS];
  const int tid = threadIdx.x;
  const int base = blockIdx.x * SCAN_ELEMS + tid * 4;
  int s = 0;
  if (base + 3 < N) {
    const int4 v = *(const int4*)(hist + base);
    s = v.x + v.y + v.z + v.w;
  } else {
    for (int j = 0; j < 4; j++) if (base + j < N) s += hist[base + j];
  }
  red[tid] = s;
  __syncthreads();
  for (int off = SCAN_BS / 2; off > 0; off >>= 1) {
    if (tid < off) red[tid] += red[tid + off];
    __syncthreads();
  }
  if (tid == 0) bsum[blockIdx.x] = red[0];
}

__global__ __launch_bounds__(1024) void scan_bsum_kernel(
    const int* __restrict__ bsum, int* __restrict__ boff, int nb) {
  __shared__ int sh[1024];
  const int tid = threadIdx.x;
  const int mine = (tid < nb) ? bsum[tid] : 0;
  sh[tid] = mine;
  __syncthreads();
  for (int off = 1; off < 1024; off <<= 1) {
    const int v = (tid >= off) ? sh[tid - off] : 0;
    __syncthreads();
    sh[tid] += v;
    __syncthreads();
  }
  if (tid < nb) boff[tid] = sh[tid] - mine;
}

__global__ __launch_bounds__(SCAN_BS) void scan_apply_kernel(
    const int* __restrict__ hist, const int* __restrict__ boff,
    int* __restrict__ offs, int* __restrict__ offs_work, int N, int E) {
  __shared__ int red[SCAN_BS];
  const int tid = threadIdx.x;
  const int base = blockIdx.x * SCAN_ELEMS + tid * 4;
  int v0 = 0, v1 = 0, v2 = 0, v3 = 0;
  if (base + 3 < N) {
    const int4 v = *(const int4*)(hist + base);
    v0 = v.x; v1 = v.y; v2 = v.z; v3 = v.w;
  } else {
    if (base < N)     v0 = hist[base];
    if (base + 1 < N) v1 = hist[base + 1];
    if (base + 2 < N) v2 = hist[base + 2];
    if (base + 3 < N) v3 = hist[base + 3];
  }
  const int s = v0 + v1 + v2 + v3;
  red[tid] = s;
  __syncthreads();
  for (int off = 1; off < SCAN_BS; off <<= 1) {
    const int v = (tid >= off) ? red[tid - off] : 0;
    __syncthreads();
    red[tid] += v;
    __syncthreads();
  }
  int run = boff[blockIdx.x] + red[tid] - s;
  if (base < N)     { offs[base] = run;     offs_work[base] = run;     run += v0; }
  if (base + 1 < N) { offs[base + 1] = run; offs_work[base + 1] = run; run += v1; }
  if (base + 2 < N) { offs[base + 2] = run; offs_work[base + 2] = run; run += v2; }
  if (base + 3 < N) { offs[base + 3] = run; offs_work[base + 3] = run; run += v3; }
  if (blockIdx.x == 0 && tid == 0) offs[N] = E;
}

__global__ void scatter_kernel(const int* __restrict__ row,
                               const int* __restrict__ col,
                               int* __restrict__ offs_work,
                               int* __restrict__ cols, int E) {
  for (int e = blockIdx.x * blockDim.x + threadIdx.x; e < E;
       e += gridDim.x * blockDim.x) {
    const int pos = atomicAdd(&offs_work[row[e]], 1);
    cols[pos] = col[e];
  }
}

// ---------- node matmuls via MFMA ----------
// gr = x@Wgr (f32) ; glpk = pack(bf16(x@Wgc+bg), bf16(x@Wl+bl))
// A-frag (16x32): lane holds A[lane&15][(lane>>4)*8+j], j=0..7
// B-frag (32x16): lane holds B[(lane>>4)*8+j][lane&15]
// D (16x16):      lane reg r -> D[(lane>>4)*4+r][lane&15]   (m89-verified)
template <bool FIRST>
__global__ __launch_bounds__(256) void node_mm3_mfma(
    const ushort* __restrict__ x, const int* __restrict__ an,
    const float* __restrict__ emb, const float* __restrict__ Wl,
    const float* __restrict__ bl, const float* __restrict__ Wgr,
    const float* __restrict__ Wgc, const float* __restrict__ bg,
    float* __restrict__ gr, uint32_t* __restrict__ glpk, int N) {
  const int tid = threadIdx.x;
  const int lane = tid & 63, wid = tid >> 6;
  const int l15 = lane & 15, kg = lane >> 4;

  // B fragments, per lane, straight from global W (48 KB, L2-resident).
  bf16x8 bfrag[3][4][2];
#pragma unroll
  for (int mat = 0; mat < 3; mat++) {
    const float* Wm = (mat == 0) ? Wl : (mat == 1) ? Wgr : Wgc;
#pragma unroll
    for (int nt = 0; nt < 4; nt++) {
#pragma unroll
      for (int ks = 0; ks < 2; ks++) {
        const float* wp = Wm + (size_t)(ks * 32 + kg * 8) * H + nt * 16 + l15;
        bf16x8 b;
#pragma unroll
        for (int j = 0; j < 8; j++) b[j] = (short)f2bf(wp[(size_t)j * H]);
        bfrag[mat][nt][ks] = b;
      }
    }
  }

  const int mbase = blockIdx.x * 64 + wid * 16;
  const int arow = mbase + l15;
  const int arow_c = min(arow, N - 1);

  // A fragments (2 K-steps of 32)
  bf16x8 afrag0, afrag1;
  if (FIRST) {
    const int a = an[arow_c];
    const float* src = emb + (size_t)a * H + kg * 8;
    const float4 u0 = *(const float4*)(src);
    const float4 u1 = *(const float4*)(src + 4);
    const float4 u2 = *(const float4*)(src + 32);
    const float4 u3 = *(const float4*)(src + 36);
    bf16x8 t0, t1;
    t0[0] = (short)f2bf(u0.x); t0[1] = (short)f2bf(u0.y);
    t0[2] = (short)f2bf(u0.z); t0[3] = (short)f2bf(u0.w);
    t0[4] = (short)f2bf(u1.x); t0[5] = (short)f2bf(u1.y);
    t0[6] = (short)f2bf(u1.z); t0[7] = (short)f2bf(u1.w);
    t1[0] = (short)f2bf(u2.x); t1[1] = (short)f2bf(u2.y);
    t1[2] = (short)f2bf(u2.z); t1[3] = (short)f2bf(u2.w);
    t1[4] = (short)f2bf(u3.x); t1[5] = (short)f2bf(u3.y);
    t1[6] = (short)f2bf(u3.z); t1[7] = (short)f2bf(u3.w);
    afrag0 = t0; afrag1 = t1;
  } else {
    const ushort* src = x + (size_t)arow_c * H + kg * 8;
    afrag0 = *(const bf16x8*)(src);
    afrag1 = *(const bf16x8*)(src + 32);
  }

  f32x4 accL[4], accR[4], accC[4];
#pragma unroll
  for (int nt = 0; nt < 4; nt++) {
    const float blv = bl[nt * 16 + l15];
    const float bgv = bg[nt * 16 + l15];
    accL[nt] = (f32x4){blv, blv, blv, blv};
    accR[nt] = (f32x4){0.f, 0.f, 0.f, 0.f};
    accC[nt] = (f32x4){bgv, bgv, bgv, bgv};
  }
#pragma unroll
  for (int nt = 0; nt < 4; nt++) {
    accL[nt] = __builtin_amdgcn_mfma_f32_16x16x32_bf16(afrag0, bfrag[0][nt][0], accL[nt], 0, 0, 0);
    accL[nt] = __builtin_amdgcn_mfma_f32_16x16x32_bf16(afrag1, bfrag[0][nt][1], accL[nt], 0, 0, 0);
    accR[nt] = __builtin_amdgcn_mfma_f32_16x16x32_bf16(afrag0, bfrag[1][nt][0], accR[nt], 0, 0, 0);
    accR[nt] = __builtin_amdgcn_mfma_f32_16x16x32_bf16(afrag1, bfrag[1][nt][1], accR[nt], 0, 0, 0);
    accC[nt] = __builtin_amdgcn_mfma_f32_16x16x32_bf16(afrag0, bfrag[2][nt][0], accC[nt], 0, 0, 0);
    accC[nt] = __builtin_amdgcn_mfma_f32_16x16x32_bf16(afrag1, bfrag[2][nt][1], accC[nt], 0, 0, 0);
  }
#pragma unroll
  for (int nt = 0; nt < 4; nt++) {
#pragma unroll
    for (int r = 0; r < 4; r++) {
      const int atom = mbase + kg * 4 + r;
      if (atom < N) {
        const size_t o = (size_t)atom * H + nt * 16 + l15;
        gr[o] = accR[nt][r];
        glpk[o] = pack_gl(accC[nt][r], accL[nt][r]);
      }
    }
  }
}

// ---------- aggregate + update: one wave per atom, lane = channel ----------
// x[i] = bf16( relu( sum_c sigmoid(gr[i]+gc[c])*lin[c] + lin_bf16[i] ) )
__global__ __launch_bounds__(256) void agg_kernel(
    const float* __restrict__ gr, const uint32_t* __restrict__ glpk,
    const int* __restrict__ offs, const int* __restrict__ cols,
    ushort* __restrict__ x, int N) {
  const int lane = threadIdx.x & 63, w = threadIdx.x >> 6;
  for (int i = blockIdx.x * 4 + w; i < N; i += gridDim.x * 4) {
    const int s = offs[i], e = offs[i + 1];
    const float gri = gr[(size_t)i * H + lane];
    float acc = 0.f;
    for (int cb = s; cb < e; cb += 64) {
      const int nchunk = min(64, e - cb);
      const int myc = (lane < nchunk) ? cols[cb + lane] : 0;
      int j = 0;
      for (; j + 3 < nchunk; j += 4) {
        const int c0 = __shfl(myc, j + 0), c1 = __shfl(myc, j + 1);
        const int c2 = __shfl(myc, j + 2), c3 = __shfl(myc, j + 3);
        const uint32_t p0 = glpk[(size_t)c0 * H + lane];
        const uint32_t p1 = glpk[(size_t)c1 * H + lane];
        const uint32_t p2 = glpk[(size_t)c2 * H + lane];
        const uint32_t p3 = glpk[(size_t)c3 * H + lane];
        acc += unpack_lin(p0) * sigmoidf_fast(gri + unpack_gc(p0));
        acc += unpack_lin(p1) * sigmoidf_fast(gri + unpack_gc(p1));
        acc += unpack_lin(p2) * sigmoidf_fast(gri + unpack_gc(p2));
        acc += unpack_lin(p3) * sigmoidf_fast(gri + unpack_gc(p3));
      }
      for (; j < nchunk; j++) {
        const int c0 = __shfl(myc, j);
        const uint32_t p0 = glpk[(size_t)c0 * H + lane];
        acc += unpack_lin(p0) * sigmoidf_fast(gri + unpack_gc(p0));
      }
    }
    const float li = unpack_lin(glpk[(size_t)i * H + lane]);
    x[(size_t)i * H + lane] = f2bf(fmaxf(acc + li, 0.f));
  }
}

// ---------- mean pool (bf16 x) ----------
__global__ void pool_kernel(const ushort* __restrict__ x,
                            float* __restrict__ pool, int N) {
  __shared__ float ps[4][64];
  const int tid = threadIdx.x, c = tid & 63, wid = tid >> 6;
  float s = 0.f;
  for (int i = blockIdx.x * 4 + wid; i < N; i += gridDim.x * 4)
    s += __uint_as_float(((uint32_t)x[(size_t)i * H + c]) << 16);
  ps[wid][c] = s;
  __syncthreads();
  if (tid < 64) {
    const float t = ps[0][tid] + ps[1][tid] + ps[2][tid] + ps[3][tid];
    atomicAdd(&pool[tid], t);
  }
}

// ---------- final MLP ----------
__global__ void mlp_kernel(const float* __restrict__ pool,
                           const float* __restrict__ W1,
                           const float* __restrict__ b1,
                           const float* __restrict__ W2,
                           const float* __restrict__ b2,
                           float* __restrict__ out, float invN) {
  __shared__ float p[64], h[64];
  const int tid = threadIdx.x;
  if (tid < 64) p[tid] = pool[tid] * invN;
  __syncthreads();
  if (tid < 64) {
    float s = b1[tid];
    for (int k = 0; k < 64; k++) s = fmaf(p[k], W1[k * 64 + tid], s);
    h[tid] = fmaxf(s, 0.f);
  }
  __syncthreads();
  float s = b2[tid];
  for (int k = 0; k < 64; k++) s = fmaf(h[k], W2[k * 128 + tid], s);
  out[tid] = s;
}

extern "C" void kernel_launch(void* const* d_in, const int* in_sizes, int n_in,
                              void* d_out, int out_size, void* d_ws,
                              size_t ws_size, hipStream_t stream) {
  const int*   an  = (const int*)d_in[0];
  const int*   ei  = (const int*)d_in[3];
  const float* emb = (const float*)d_in[4];
  const float* Wl  = (const float*)d_in[5];
  const float* bl  = (const float*)d_in[6];
  const float* Wg  = (const float*)d_in[7];
  const float* bg  = (const float*)d_in[8];
  const float* W1  = (const float*)d_in[9];
  const float* b1  = (const float*)d_in[10];
  const float* W2  = (const float*)d_in[11];
  const float* b2  = (const float*)d_in[12];
  float* out = (float*)d_out;

  const int N = in_sizes[0];
  const int E = in_sizes[3] / 2;
  const int* row = ei;
  const int* col = ei + E;

  const size_t NH = (size_t)N * H;
  char* ws = (char*)d_ws;
  ushort*   x    = (ushort*)(ws);                 // bf16 [N][64]
  float*    gr   = (float*)(ws + NH * 2);         // f32  [N][64]
  uint32_t* glpk = (uint32_t*)(ws + NH * 2 + NH * 4);
  char* p = ws + NH * 2 + NH * 4 + NH * 4;
  int* hist      = (int*)p;  p += ((size_t)N + 1) * 4;
  int* offs      = (int*)p;  p += ((size_t)N + 1) * 4;
  int* offs_work = (int*)p;  p += ((size_t)N + 1) * 4;
  int* cols      = (int*)p;  p += (size_t)E * 4;
  int* bsum      = (int*)p;  p += 4096;
  int* boff      = (int*)p;  p += 4096;
  float* pool    = (float*)p;
  // total ≈ 12.8 + 25.6 + 25.6 + 1.2 + 4 MB ≈ 69 MB

  // CSR build (edges identical every layer)
  const int nb = (N + SCAN_ELEMS - 1) / SCAN_ELEMS;
  hipMemsetAsync(hist, 0, (size_t)N * 4, stream);
  hist_kernel<<<2048, 256, 0, stream>>>(row, hist, E);
  scan_partial_kernel<<<nb, SCAN_BS, 0, stream>>>(hist, bsum, N);
  scan_bsum_kernel<<<1, 1024, 0, stream>>>(bsum, boff, nb);
  scan_apply_kernel<<<nb, SCAN_BS, 0, stream>>>(hist, boff, offs, offs_work, N, E);
  scatter_kernel<<<2048, 256, 0, stream>>>(row, col, offs_work, cols, E);

  const int mmGrid = (N + 63) / 64;
  const int aggGrid = (N + 3) / 4;
  for (int l = 0; l < 3; l++) {
    const float* Wl_l  = Wl + (size_t)l * H * H;
    const float* bl_l  = bl + (size_t)l * H;
    const float* Wgr_l = Wg + (size_t)l * 2 * H * H;
    const float* Wgc_l = Wgr_l + H * H;
    const float* bg_l  = bg + (size_t)l * H;
    if (l == 0)
      node_mm3_mfma<true><<<mmGrid, 256, 0, stream>>>(
          x, an, emb, Wl_l, bl_l, Wgr_l, Wgc_l, bg_l, gr, glpk, N);
    else
      node_mm3_mfma<false><<<mmGrid, 256, 0, stream>>>(
          x, an, emb, Wl_l, bl_l, Wgr_l, Wgc_l, bg_l, gr, glpk, N);
    agg_kernel<<<aggGrid, 256, 0, stream>>>(gr, glpk, offs, cols, x, N);
  }

  hipMemsetAsync(pool, 0, 64 * sizeof(float), stream);
  pool_kernel<<<1024, 256, 0, stream>>>(x, pool, N);
  mlp_kernel<<<1, 128, 0, stream>>>(pool, W1, b1, W2, b2, out, 1.0f / (float)N);
}

// Round 7
// 403.706 us; speedup vs baseline: 7.2366x; 1.1025x over previous
//
#include <hip/hip_runtime.h>
#include <hip/hip_bf16.h>
#include <stdint.h>

// CrystalGraphEncoder on MI355X — round 6 (resubmit after broker timeout):
//  R5 post-mortem: scatter_kernel 62us, WRITE 70MB for 4MB payload (16x line
//  amplification from random 4B writes). Fix: 2-level bucketed CSR build:
//   k1 bucket_hist (782 buckets of 128 rows, LDS-aggregated)
//   k2 bucket_scan (1 block)
//   k3 bucket_scatter: (row,col)->ebuf grouped by bucket, per-block LDS counts
//      + one global reservation per (block,bucket) => ~1.7x write amp not 16x
//   k4 csr_build: per bucket, exact in-LDS CSR; cols written into the bucket's
//      block-exclusive contiguous window (L2-coalesced), offs sequential.
//  mm3 (MFMA) and agg unchanged from R5.
//
// ws: x_bf16 | gr | glpk | offs | cols | bcnt | bstart | bcur | ebuf | pool (~77MB)

#define H 64
#define BSHIFT 7
#define BROWS 128  // rows per bucket

typedef __attribute__((ext_vector_type(8))) short bf16x8;
typedef __attribute__((ext_vector_type(4))) float f32x4;

__device__ __forceinline__ float sigmoidf_fast(float z) {
  return __builtin_amdgcn_rcpf(1.f + __expf(-z));
}

__device__ __forceinline__ ushort f2bf(float f) {  // RNE
  uint32_t u = __float_as_uint(f);
  u = (u + 0x7fffu + ((u >> 16) & 1u)) >> 16;
  return (ushort)u;
}
// pack: hi16 = bf16(lin), lo16 = bf16(gc)
__device__ __forceinline__ uint32_t pack_gl(float gc, float lin) {
  uint32_t ug = __float_as_uint(gc);
  ug = (ug + 0x7fffu + ((ug >> 16) & 1u)) >> 16;
  uint32_t ul = __float_as_uint(lin);
  ul = ((ul + 0x7fffu + ((ul >> 16) & 1u)) >> 16) << 16;
  return ul | ug;
}
__device__ __forceinline__ float unpack_gc(uint32_t p) {
  return __uint_as_float(p << 16);
}
__device__ __forceinline__ float unpack_lin(uint32_t p) {
  return __uint_as_float(p & 0xffff0000u);
}

// ---------- k1: bucket histogram (LDS-aggregated) ----------
__global__ __launch_bounds__(256) void bucket_hist_kernel(
    const int* __restrict__ row, int* __restrict__ bcnt, int E, int nbuck) {
  __shared__ int cnt[1024];
  const int tid = threadIdx.x;
  for (int b = tid; b < nbuck; b += 256) cnt[b] = 0;
  __syncthreads();
  for (int e = blockIdx.x * blockDim.x + tid; e < E; e += gridDim.x * blockDim.x)
    atomicAdd(&cnt[row[e] >> BSHIFT], 1);
  __syncthreads();
  for (int b = tid; b < nbuck; b += 256)
    if (cnt[b]) atomicAdd(&bcnt[b], cnt[b]);
}

// ---------- k2: scan bucket counts (1 block; nbuck <= 1024) ----------
__global__ __launch_bounds__(1024) void bucket_scan_kernel(
    const int* __restrict__ bcnt, int* __restrict__ bstart,
    int* __restrict__ bcur, int* __restrict__ offs, int nbuck, int N, int E) {
  __shared__ int sh[1024];
  const int tid = threadIdx.x;
  const int mine = (tid < nbuck) ? bcnt[tid] : 0;
  sh[tid] = mine;
  __syncthreads();
  for (int off = 1; off < 1024; off <<= 1) {
    const int v = (tid >= off) ? sh[tid - off] : 0;
    __syncthreads();
    sh[tid] += v;
    __syncthreads();
  }
  if (tid < nbuck) {
    const int ex = sh[tid] - mine;
    bstart[tid] = ex;
    bcur[tid] = ex;
  }
  if (tid == 0) {
    bstart[nbuck] = E;
    offs[N] = E;
  }
}

// ---------- k3: bucket scatter with per-block grouping ----------
#define SCHUNK 4096
__global__ __launch_bounds__(256) void bucket_scatter_kernel(
    const int* __restrict__ row, const int* __restrict__ col,
    int* __restrict__ bcur, uint2* __restrict__ ebuf, int E, int nbuck) {
  __shared__ int cnt[1024], base[1024];
  const int tid = threadIdx.x;
  const int start = blockIdx.x * SCHUNK;
  const int end = min(start + SCHUNK, E);
  for (int b = tid; b < nbuck; b += 256) cnt[b] = 0;
  __syncthreads();
  for (int e = start + tid; e < end; e += 256)
    atomicAdd(&cnt[row[e] >> BSHIFT], 1);
  __syncthreads();
  for (int b = tid; b < nbuck; b += 256) {
    if (cnt[b]) base[b] = atomicAdd(&bcur[b], cnt[b]);
    cnt[b] = 0;
  }
  __syncthreads();
  for (int e = start + tid; e < end; e += 256) {
    const int r = row[e];
    const int b = r >> BSHIFT;
    const int pos = base[b] + atomicAdd(&cnt[b], 1);
    ebuf[pos] = make_uint2((uint32_t)r, (uint32_t)col[e]);
  }
}

// ---------- k4: per-bucket exact CSR (one block per bucket) ----------
__global__ __launch_bounds__(256) void csr_build_kernel(
    const uint2* __restrict__ ebuf, const int* __restrict__ bstart,
    int* __restrict__ offs, int* __restrict__ cols, int N) {
  __shared__ int cnt[BROWS], sc[BROWS];
  const int tid = threadIdx.x;
  const int b = blockIdx.x;
  const int bs = bstart[b], be = bstart[b + 1];
  const int rowbase = b << BSHIFT;
  if (tid < BROWS) cnt[tid] = 0;
  __syncthreads();
  for (int e = bs + tid; e < be; e += 256)
    atomicAdd(&cnt[ebuf[e].x & (BROWS - 1)], 1);
  __syncthreads();
  if (tid < BROWS) sc[tid] = cnt[tid];
  __syncthreads();
  for (int off = 1; off < BROWS; off <<= 1) {
    const int v = (tid >= off && tid < BROWS) ? sc[tid - off] : 0;
    __syncthreads();
    if (tid < BROWS) sc[tid] += v;
    __syncthreads();
  }
  if (tid < BROWS) {
    sc[tid] -= cnt[tid];  // exclusive
    cnt[tid] = 0;         // reuse as cursor
    const int r = rowbase + tid;
    if (r < N) offs[r] = bs + sc[tid];
  }
  __syncthreads();
  for (int e = bs + tid; e < be; e += 256) {
    const uint2 u = ebuf[e];
    const int rl = u.x & (BROWS - 1);
    const int pos = sc[rl] + atomicAdd(&cnt[rl], 1);
    cols[bs + pos] = (int)u.y;
  }
}

// ---------- node matmuls via MFMA (unchanged from R5) ----------
template <bool FIRST>
__global__ __launch_bounds__(256) void node_mm3_mfma(
    const ushort* __restrict__ x, const int* __restrict__ an,
    const float* __restrict__ emb, const float* __restrict__ Wl,
    const float* __restrict__ bl, const float* __restrict__ Wgr,
    const float* __restrict__ Wgc, const float* __restrict__ bg,
    float* __restrict__ gr, uint32_t* __restrict__ glpk, int N) {
  const int tid = threadIdx.x;
  const int lane = tid & 63, wid = tid >> 6;
  const int l15 = lane & 15, kg = lane >> 4;

  bf16x8 bfrag[3][4][2];
#pragma unroll
  for (int mat = 0; mat < 3; mat++) {
    const float* Wm = (mat == 0) ? Wl : (mat == 1) ? Wgr : Wgc;
#pragma unroll
    for (int nt = 0; nt < 4; nt++) {
#pragma unroll
      for (int ks = 0; ks < 2; ks++) {
        const float* wp = Wm + (size_t)(ks * 32 + kg * 8) * H + nt * 16 + l15;
        bf16x8 bb;
#pragma unroll
        for (int j = 0; j < 8; j++) bb[j] = (short)f2bf(wp[(size_t)j * H]);
        bfrag[mat][nt][ks] = bb;
      }
    }
  }

  const int mbase = blockIdx.x * 64 + wid * 16;
  const int arow = mbase + l15;
  const int arow_c = min(arow, N - 1);

  bf16x8 afrag0, afrag1;
  if (FIRST) {
    const int a = an[arow_c];
    const float* src = emb + (size_t)a * H + kg * 8;
    const float4 u0 = *(const float4*)(src);
    const float4 u1 = *(const float4*)(src + 4);
    const float4 u2 = *(const float4*)(src + 32);
    const float4 u3 = *(const float4*)(src + 36);
    bf16x8 t0, t1;
    t0[0] = (short)f2bf(u0.x); t0[1] = (short)f2bf(u0.y);
    t0[2] = (short)f2bf(u0.z); t0[3] = (short)f2bf(u0.w);
    t0[4] = (short)f2bf(u1.x); t0[5] = (short)f2bf(u1.y);
    t0[6] = (short)f2bf(u1.z); t0[7] = (short)f2bf(u1.w);
    t1[0] = (short)f2bf(u2.x); t1[1] = (short)f2bf(u2.y);
    t1[2] = (short)f2bf(u2.z); t1[3] = (short)f2bf(u2.w);
    t1[4] = (short)f2bf(u3.x); t1[5] = (short)f2bf(u3.y);
    t1[6] = (short)f2bf(u3.z); t1[7] = (short)f2bf(u3.w);
    afrag0 = t0; afrag1 = t1;
  } else {
    const ushort* src = x + (size_t)arow_c * H + kg * 8;
    afrag0 = *(const bf16x8*)(src);
    afrag1 = *(const bf16x8*)(src + 32);
  }

  f32x4 accL[4], accR[4], accC[4];
#pragma unroll
  for (int nt = 0; nt < 4; nt++) {
    const float blv = bl[nt * 16 + l15];
    const float bgv = bg[nt * 16 + l15];
    accL[nt] = (f32x4){blv, blv, blv, blv};
    accR[nt] = (f32x4){0.f, 0.f, 0.f, 0.f};
    accC[nt] = (f32x4){bgv, bgv, bgv, bgv};
  }
#pragma unroll
  for (int nt = 0; nt < 4; nt++) {
    accL[nt] = __builtin_amdgcn_mfma_f32_16x16x32_bf16(afrag0, bfrag[0][nt][0], accL[nt], 0, 0, 0);
    accL[nt] = __builtin_amdgcn_mfma_f32_16x16x32_bf16(afrag1, bfrag[0][nt][1], accL[nt], 0, 0, 0);
    accR[nt] = __builtin_amdgcn_mfma_f32_16x16x32_bf16(afrag0, bfrag[1][nt][0], accR[nt], 0, 0, 0);
    accR[nt] = __builtin_amdgcn_mfma_f32_16x16x32_bf16(afrag1, bfrag[1][nt][1], accR[nt], 0, 0, 0);
    accC[nt] = __builtin_amdgcn_mfma_f32_16x16x32_bf16(afrag0, bfrag[2][nt][0], accC[nt], 0, 0, 0);
    accC[nt] = __builtin_amdgcn_mfma_f32_16x16x32_bf16(afrag1, bfrag[2][nt][1], accC[nt], 0, 0, 0);
  }
#pragma unroll
  for (int nt = 0; nt < 4; nt++) {
#pragma unroll
    for (int r = 0; r < 4; r++) {
      const int atom = mbase + kg * 4 + r;
      if (atom < N) {
        const size_t o = (size_t)atom * H + nt * 16 + l15;
        gr[o] = accR[nt][r];
        glpk[o] = pack_gl(accC[nt][r], accL[nt][r]);
      }
    }
  }
}

// ---------- aggregate + update (unchanged from R5) ----------
__global__ __launch_bounds__(256) void agg_kernel(
    const float* __restrict__ gr, const uint32_t* __restrict__ glpk,
    const int* __restrict__ offs, const int* __restrict__ cols,
    ushort* __restrict__ x, int N) {
  const int lane = threadIdx.x & 63, w = threadIdx.x >> 6;
  for (int i = blockIdx.x * 4 + w; i < N; i += gridDim.x * 4) {
    const int s = offs[i], e = offs[i + 1];
    const float gri = gr[(size_t)i * H + lane];
    float acc = 0.f;
    for (int cb = s; cb < e; cb += 64) {
      const int nchunk = min(64, e - cb);
      const int myc = (lane < nchunk) ? cols[cb + lane] : 0;
      int j = 0;
      for (; j + 3 < nchunk; j += 4) {
        const int c0 = __shfl(myc, j + 0), c1 = __shfl(myc, j + 1);
        const int c2 = __shfl(myc, j + 2), c3 = __shfl(myc, j + 3);
        const uint32_t p0 = glpk[(size_t)c0 * H + lane];
        const uint32_t p1 = glpk[(size_t)c1 * H + lane];
        const uint32_t p2 = glpk[(size_t)c2 * H + lane];
        const uint32_t p3 = glpk[(size_t)c3 * H + lane];
        acc += unpack_lin(p0) * sigmoidf_fast(gri + unpack_gc(p0));
        acc += unpack_lin(p1) * sigmoidf_fast(gri + unpack_gc(p1));
        acc += unpack_lin(p2) * sigmoidf_fast(gri + unpack_gc(p2));
        acc += unpack_lin(p3) * sigmoidf_fast(gri + unpack_gc(p3));
      }
      for (; j < nchunk; j++) {
        const int c0 = __shfl(myc, j);
        const uint32_t p0 = glpk[(size_t)c0 * H + lane];
        acc += unpack_lin(p0) * sigmoidf_fast(gri + unpack_gc(p0));
      }
    }
    const float li = unpack_lin(glpk[(size_t)i * H + lane]);
    x[(size_t)i * H + lane] = f2bf(fmaxf(acc + li, 0.f));
  }
}

// ---------- mean pool (bf16 x) ----------
__global__ void pool_kernel(const ushort* __restrict__ x,
                            float* __restrict__ pool, int N) {
  __shared__ float ps[4][64];
  const int tid = threadIdx.x, c = tid & 63, wid = tid >> 6;
  float s = 0.f;
  for (int i = blockIdx.x * 4 + wid; i < N; i += gridDim.x * 4)
    s += __uint_as_float(((uint32_t)x[(size_t)i * H + c]) << 16);
  ps[wid][c] = s;
  __syncthreads();
  if (tid < 64) {
    const float t = ps[0][tid] + ps[1][tid] + ps[2][tid] + ps[3][tid];
    atomicAdd(&pool[tid], t);
  }
}

// ---------- final MLP ----------
__global__ void mlp_kernel(const float* __restrict__ pool,
                           const float* __restrict__ W1,
                           const float* __restrict__ b1,
                           const float* __restrict__ W2,
                           const float* __restrict__ b2,
                           float* __restrict__ out, float invN) {
  __shared__ float p[64], h[64];
  const int tid = threadIdx.x;
  if (tid < 64) p[tid] = pool[tid] * invN;
  __syncthreads();
  if (tid < 64) {
    float s = b1[tid];
    for (int k = 0; k < 64; k++) s = fmaf(p[k], W1[k * 64 + tid], s);
    h[tid] = fmaxf(s, 0.f);
  }
  __syncthreads();
  float s = b2[tid];
  for (int k = 0; k < 64; k++) s = fmaf(h[k], W2[k * 128 + tid], s);
  out[tid] = s;
}

extern "C" void kernel_launch(void* const* d_in, const int* in_sizes, int n_in,
                              void* d_out, int out_size, void* d_ws,
                              size_t ws_size, hipStream_t stream) {
  const int*   an  = (const int*)d_in[0];
  const int*   ei  = (const int*)d_in[3];
  const float* emb = (const float*)d_in[4];
  const float* Wl  = (const float*)d_in[5];
  const float* bl  = (const float*)d_in[6];
  const float* Wg  = (const float*)d_in[7];
  const float* bg  = (const float*)d_in[8];
  const float* W1  = (const float*)d_in[9];
  const float* b1  = (const float*)d_in[10];
  const float* W2  = (const float*)d_in[11];
  const float* b2  = (const float*)d_in[12];
  float* out = (float*)d_out;

  const int N = in_sizes[0];
  const int E = in_sizes[3] / 2;
  const int* row = ei;
  const int* col = ei + E;
  const int nbuck = (N + BROWS - 1) >> BSHIFT;  // 782 for N=100K (<=1024)

  const size_t NH = (size_t)N * H;
  char* ws = (char*)d_ws;
  ushort*   x    = (ushort*)(ws);
  float*    gr   = (float*)(ws + NH * 2);
  uint32_t* glpk = (uint32_t*)(ws + NH * 2 + NH * 4);
  char* p = ws + NH * 2 + NH * 4 + NH * 4;
  int*   offs   = (int*)p;   p += ((size_t)N + 1) * 4;
  int*   cols   = (int*)p;   p += (size_t)E * 4;
  int*   bcnt   = (int*)p;   p += 4096;
  int*   bstart = (int*)p;   p += 4100;
  int*   bcur   = (int*)p;   p += 4096;
  uint2* ebuf   = (uint2*)p; p += (size_t)E * 8;
  float* pool   = (float*)p;
  // total ≈ 12.8 + 25.6 + 25.6 + 0.4 + 4 + 8 MB + ~13KB ≈ 76.5 MB

  // --- CSR build (2-level bucketed; edges identical every layer) ---
  hipMemsetAsync(bcnt, 0, (size_t)nbuck * 4, stream);
  bucket_hist_kernel<<<1024, 256, 0, stream>>>(row, bcnt, E, nbuck);
  bucket_scan_kernel<<<1, 1024, 0, stream>>>(bcnt, bstart, bcur, offs, nbuck, N, E);
  bucket_scatter_kernel<<<(E + SCHUNK - 1) / SCHUNK, 256, 0, stream>>>(
      row, col, bcur, ebuf, E, nbuck);
  csr_build_kernel<<<nbuck, 256, 0, stream>>>(ebuf, bstart, offs, cols, N);

  const int mmGrid = (N + 63) / 64;
  const int aggGrid = (N + 3) / 4;
  for (int l = 0; l < 3; l++) {
    const float* Wl_l  = Wl + (size_t)l * H * H;
    const float* bl_l  = bl + (size_t)l * H;
    const float* Wgr_l = Wg + (size_t)l * 2 * H * H;
    const float* Wgc_l = Wgr_l + H * H;
    const float* bg_l  = bg + (size_t)l * H;
    if (l == 0)
      node_mm3_mfma<true><<<mmGrid, 256, 0, stream>>>(
          x, an, emb, Wl_l, bl_l, Wgr_l, Wgc_l, bg_l, gr, glpk, N);
    else
      node_mm3_mfma<false><<<mmGrid, 256, 0, stream>>>(
          x, an, emb, Wl_l, bl_l, Wgr_l, Wgc_l, bg_l, gr, glpk, N);
    agg_kernel<<<aggGrid, 256, 0, stream>>>(gr, glpk, offs, cols, x, N);
  }

  hipMemsetAsync(pool, 0, 64 * sizeof(float), stream);
  pool_kernel<<<1024, 256, 0, stream>>>(x, pool, N);
  mlp_kernel<<<1, 128, 0, stream>>>(pool, W1, b1, W2, b2, out, 1.0f / (float)N);
}

// Round 8
// 400.851 us; speedup vs baseline: 7.2881x; 1.0071x over previous
//
#include <hip/hip_runtime.h>
#include <hip/hip_bf16.h>
#include <stdint.h>

// CrystalGraphEncoder on MI355X — round 8:
//  R7 post-mortem: agg=54us (FETCH 137MB, VALU 52%); mm3 suspect ~45us each
//  from 576-inst per-thread B-frag build. Fixes:
//   1. prep_kernel: all W -> bf16 in frag-ready layout (mm3 B-frags = 24
//      coalesced dwordx4 loads); Wgr/Wgc/bg pre-scaled by -log2(e).
//   2. agg sigmoid via exp2 (no mul/neg), 8-deep gather unroll.
//   3. pool zeroing folded into bucket_scan (one fewer dispatch).
//
// ws: x_bf16 | gr | glpk | offs | cols | bcnt | bstart | bcur | ebuf | wprep | bgs | pool

#define H 64
#define BSHIFT 7
#define BROWS 128
#define NLOG2E -1.4426950408889634f

typedef __attribute__((ext_vector_type(8))) short bf16x8;
typedef __attribute__((ext_vector_type(4))) float f32x4;

__device__ __forceinline__ ushort f2bf(float f) {  // RNE
  uint32_t u = __float_as_uint(f);
  u = (u + 0x7fffu + ((u >> 16) & 1u)) >> 16;
  return (ushort)u;
}
// pack: hi16 = bf16(lin), lo16 = bf16(gc)
__device__ __forceinline__ uint32_t pack_gl(float gc, float lin) {
  uint32_t ug = __float_as_uint(gc);
  ug = (ug + 0x7fffu + ((ug >> 16) & 1u)) >> 16;
  uint32_t ul = __float_as_uint(lin);
  ul = ((ul + 0x7fffu + ((ul >> 16) & 1u)) >> 16) << 16;
  return ul | ug;
}
__device__ __forceinline__ float unpack_gc(uint32_t p) {
  return __uint_as_float(p << 16);
}
__device__ __forceinline__ float unpack_lin(uint32_t p) {
  return __uint_as_float(p & 0xffff0000u);
}
// arg already holds -log2e*(gr+gc): sigmoid = 1/(1+2^arg)
__device__ __forceinline__ float sig_from_neglog2(float arg) {
  return __builtin_amdgcn_rcpf(1.f + exp2f(arg));
}

// ---------- prep: W -> bf16 frag layout; gate mats scaled by -log2e ----------
// wprep[l][mat][nt][ks][lane] : bf16x8, value[j]=bf16(W[(ks*32+kg*8+j)*64+nt*16+l15]*s)
__global__ __launch_bounds__(256) void prep_kernel(
    const float* __restrict__ Wl, const float* __restrict__ Wg,
    const float* __restrict__ bg, bf16x8* __restrict__ wprep,
    float* __restrict__ bgs) {
  const int t = blockIdx.x * 256 + threadIdx.x;
  if (t < 192) bgs[t] = bg[t] * NLOG2E;  // 3 layers x 64
  if (t >= 4608) return;
  const int l = t / 1536;
  const int rem = t - l * 1536;
  const int mat = rem >> 9;
  const int rem2 = rem & 511;
  const int nt = rem2 >> 7;
  const int ks = (rem2 >> 6) & 1;
  const int lane = rem2 & 63;
  const int kg = lane >> 4, l15 = lane & 15;
  const float* src;
  float s;
  if (mat == 0)      { src = Wl + (size_t)l * 4096;        s = 1.f; }
  else if (mat == 1) { src = Wg + (size_t)l * 8192;        s = NLOG2E; }
  else               { src = Wg + (size_t)l * 8192 + 4096; s = NLOG2E; }
  bf16x8 v;
#pragma unroll
  for (int j = 0; j < 8; j++)
    v[j] = (short)f2bf(src[(size_t)(ks * 32 + kg * 8 + j) * 64 + nt * 16 + l15] * s);
  wprep[t] = v;
}

// ---------- k1: bucket histogram ----------
__global__ __launch_bounds__(256) void bucket_hist_kernel(
    const int* __restrict__ row, int* __restrict__ bcnt, int E, int nbuck) {
  __shared__ int cnt[1024];
  const int tid = threadIdx.x;
  for (int b = tid; b < nbuck; b += 256) cnt[b] = 0;
  __syncthreads();
  for (int e = blockIdx.x * blockDim.x + tid; e < E; e += gridDim.x * blockDim.x)
    atomicAdd(&cnt[row[e] >> BSHIFT], 1);
  __syncthreads();
  for (int b = tid; b < nbuck; b += 256)
    if (cnt[b]) atomicAdd(&bcnt[b], cnt[b]);
}

// ---------- k2: scan bucket counts (+pool zero) ----------
__global__ __launch_bounds__(1024) void bucket_scan_kernel(
    const int* __restrict__ bcnt, int* __restrict__ bstart,
    int* __restrict__ bcur, int* __restrict__ offs, float* __restrict__ pool,
    int nbuck, int N, int E) {
  __shared__ int sh[1024];
  const int tid = threadIdx.x;
  if (tid < 64) pool[tid] = 0.f;
  const int mine = (tid < nbuck) ? bcnt[tid] : 0;
  sh[tid] = mine;
  __syncthreads();
  for (int off = 1; off < 1024; off <<= 1) {
    const int v = (tid >= off) ? sh[tid - off] : 0;
    __syncthreads();
    sh[tid] += v;
    __syncthreads();
  }
  if (tid < nbuck) {
    const int ex = sh[tid] - mine;
    bstart[tid] = ex;
    bcur[tid] = ex;
  }
  if (tid == 0) {
    bstart[nbuck] = E;
    offs[N] = E;
  }
}

// ---------- k3: bucket scatter ----------
#define SCHUNK 4096
__global__ __launch_bounds__(256) void bucket_scatter_kernel(
    const int* __restrict__ row, const int* __restrict__ col,
    int* __restrict__ bcur, uint2* __restrict__ ebuf, int E, int nbuck) {
  __shared__ int cnt[1024], base[1024];
  const int tid = threadIdx.x;
  const int start = blockIdx.x * SCHUNK;
  const int end = min(start + SCHUNK, E);
  for (int b = tid; b < nbuck; b += 256) cnt[b] = 0;
  __syncthreads();
  for (int e = start + tid; e < end; e += 256)
    atomicAdd(&cnt[row[e] >> BSHIFT], 1);
  __syncthreads();
  for (int b = tid; b < nbuck; b += 256) {
    if (cnt[b]) base[b] = atomicAdd(&bcur[b], cnt[b]);
    cnt[b] = 0;
  }
  __syncthreads();
  for (int e = start + tid; e < end; e += 256) {
    const int r = row[e];
    const int b = r >> BSHIFT;
    const int pos = base[b] + atomicAdd(&cnt[b], 1);
    ebuf[pos] = make_uint2((uint32_t)r, (uint32_t)col[e]);
  }
}

// ---------- k4: per-bucket exact CSR ----------
__global__ __launch_bounds__(256) void csr_build_kernel(
    const uint2* __restrict__ ebuf, const int* __restrict__ bstart,
    int* __restrict__ offs, int* __restrict__ cols, int N) {
  __shared__ int cnt[BROWS], sc[BROWS];
  const int tid = threadIdx.x;
  const int b = blockIdx.x;
  const int bs = bstart[b], be = bstart[b + 1];
  const int rowbase = b << BSHIFT;
  if (tid < BROWS) cnt[tid] = 0;
  __syncthreads();
  for (int e = bs + tid; e < be; e += 256)
    atomicAdd(&cnt[ebuf[e].x & (BROWS - 1)], 1);
  __syncthreads();
  if (tid < BROWS) sc[tid] = cnt[tid];
  __syncthreads();
  for (int off = 1; off < BROWS; off <<= 1) {
    const int v = (tid >= off && tid < BROWS) ? sc[tid - off] : 0;
    __syncthreads();
    if (tid < BROWS) sc[tid] += v;
    __syncthreads();
  }
  if (tid < BROWS) {
    sc[tid] -= cnt[tid];
    cnt[tid] = 0;
    const int r = rowbase + tid;
    if (r < N) offs[r] = bs + sc[tid];
  }
  __syncthreads();
  for (int e = bs + tid; e < be; e += 256) {
    const uint2 u = ebuf[e];
    const int rl = u.x & (BROWS - 1);
    const int pos = sc[rl] + atomicAdd(&cnt[rl], 1);
    cols[bs + pos] = (int)u.y;
  }
}

// ---------- node matmuls via MFMA, B-frags from prepped buffer ----------
template <bool FIRST>
__global__ __launch_bounds__(256) void node_mm3_mfma(
    const ushort* __restrict__ x, const int* __restrict__ an,
    const float* __restrict__ emb, const bf16x8* __restrict__ wp,
    const float* __restrict__ bl, const float* __restrict__ bgs,
    float* __restrict__ gr, uint32_t* __restrict__ glpk, int N) {
  const int tid = threadIdx.x;
  const int lane = tid & 63, wid = tid >> 6;
  const int l15 = lane & 15, kg = lane >> 4;

  bf16x8 bfrag[3][4][2];
#pragma unroll
  for (int mat = 0; mat < 3; mat++)
#pragma unroll
    for (int nt = 0; nt < 4; nt++)
#pragma unroll
      for (int ks = 0; ks < 2; ks++)
        bfrag[mat][nt][ks] = wp[(((mat * 4 + nt) * 2 + ks) << 6) + lane];

  const int mbase = blockIdx.x * 64 + wid * 16;
  const int arow = mbase + l15;
  const int arow_c = min(arow, N - 1);

  bf16x8 afrag0, afrag1;
  if (FIRST) {
    const int a = an[arow_c];
    const float* src = emb + (size_t)a * H + kg * 8;
    const float4 u0 = *(const float4*)(src);
    const float4 u1 = *(const float4*)(src + 4);
    const float4 u2 = *(const float4*)(src + 32);
    const float4 u3 = *(const float4*)(src + 36);
    bf16x8 t0, t1;
    t0[0] = (short)f2bf(u0.x); t0[1] = (short)f2bf(u0.y);
    t0[2] = (short)f2bf(u0.z); t0[3] = (short)f2bf(u0.w);
    t0[4] = (short)f2bf(u1.x); t0[5] = (short)f2bf(u1.y);
    t0[6] = (short)f2bf(u1.z); t0[7] = (short)f2bf(u1.w);
    t1[0] = (short)f2bf(u2.x); t1[1] = (short)f2bf(u2.y);
    t1[2] = (short)f2bf(u2.z); t1[3] = (short)f2bf(u2.w);
    t1[4] = (short)f2bf(u3.x); t1[5] = (short)f2bf(u3.y);
    t1[6] = (short)f2bf(u3.z); t1[7] = (short)f2bf(u3.w);
    afrag0 = t0; afrag1 = t1;
  } else {
    const ushort* src = x + (size_t)arow_c * H + kg * 8;
    afrag0 = *(const bf16x8*)(src);
    afrag1 = *(const bf16x8*)(src + 32);
  }

  f32x4 accL[4], accR[4], accC[4];
#pragma unroll
  for (int nt = 0; nt < 4; nt++) {
    const float blv = bl[nt * 16 + l15];
    const float bgv = bgs[nt * 16 + l15];
    accL[nt] = (f32x4){blv, blv, blv, blv};
    accR[nt] = (f32x4){0.f, 0.f, 0.f, 0.f};
    accC[nt] = (f32x4){bgv, bgv, bgv, bgv};
  }
#pragma unroll
  for (int nt = 0; nt < 4; nt++) {
    accL[nt] = __builtin_amdgcn_mfma_f32_16x16x32_bf16(afrag0, bfrag[0][nt][0], accL[nt], 0, 0, 0);
    accL[nt] = __builtin_amdgcn_mfma_f32_16x16x32_bf16(afrag1, bfrag[0][nt][1], accL[nt], 0, 0, 0);
    accR[nt] = __builtin_amdgcn_mfma_f32_16x16x32_bf16(afrag0, bfrag[1][nt][0], accR[nt], 0, 0, 0);
    accR[nt] = __builtin_amdgcn_mfma_f32_16x16x32_bf16(afrag1, bfrag[1][nt][1], accR[nt], 0, 0, 0);
    accC[nt] = __builtin_amdgcn_mfma_f32_16x16x32_bf16(afrag0, bfrag[2][nt][0], accC[nt], 0, 0, 0);
    accC[nt] = __builtin_amdgcn_mfma_f32_16x16x32_bf16(afrag1, bfrag[2][nt][1], accC[nt], 0, 0, 0);
  }
#pragma unroll
  for (int nt = 0; nt < 4; nt++) {
#pragma unroll
    for (int r = 0; r < 4; r++) {
      const int atom = mbase + kg * 4 + r;
      if (atom < N) {
        const size_t o = (size_t)atom * H + nt * 16 + l15;
        gr[o] = accR[nt][r];
        glpk[o] = pack_gl(accC[nt][r], accL[nt][r]);
      }
    }
  }
}

// ---------- aggregate + update; gate args pre-scaled by -log2e ----------
__global__ __launch_bounds__(256) void agg_kernel(
    const float* __restrict__ gr, const uint32_t* __restrict__ glpk,
    const int* __restrict__ offs, const int* __restrict__ cols,
    ushort* __restrict__ x, int N) {
  const int lane = threadIdx.x & 63, w = threadIdx.x >> 6;
  for (int i = blockIdx.x * 4 + w; i < N; i += gridDim.x * 4) {
    const int s = offs[i], e = offs[i + 1];
    const float gri = gr[(size_t)i * H + lane];
    float acc = 0.f;
    for (int cb = s; cb < e; cb += 64) {
      const int nchunk = min(64, e - cb);
      const int myc = (lane < nchunk) ? cols[cb + lane] : 0;
      int j = 0;
      for (; j + 7 < nchunk; j += 8) {
        uint32_t p[8];
#pragma unroll
        for (int q = 0; q < 8; q++) {
          const int c = __shfl(myc, j + q);
          p[q] = glpk[(size_t)c * H + lane];
        }
#pragma unroll
        for (int q = 0; q < 8; q++)
          acc += unpack_lin(p[q]) * sig_from_neglog2(gri + unpack_gc(p[q]));
      }
      for (; j < nchunk; j++) {
        const int c = __shfl(myc, j);
        const uint32_t p0 = glpk[(size_t)c * H + lane];
        acc += unpack_lin(p0) * sig_from_neglog2(gri + unpack_gc(p0));
      }
    }
    const float li = unpack_lin(glpk[(size_t)i * H + lane]);
    x[(size_t)i * H + lane] = f2bf(fmaxf(acc + li, 0.f));
  }
}

// ---------- mean pool (bf16 x) ----------
__global__ void pool_kernel(const ushort* __restrict__ x,
                            float* __restrict__ pool, int N) {
  __shared__ float ps[4][64];
  const int tid = threadIdx.x, c = tid & 63, wid = tid >> 6;
  float s = 0.f;
  for (int i = blockIdx.x * 4 + wid; i < N; i += gridDim.x * 4)
    s += __uint_as_float(((uint32_t)x[(size_t)i * H + c]) << 16);
  ps[wid][c] = s;
  __syncthreads();
  if (tid < 64) {
    const float t = ps[0][tid] + ps[1][tid] + ps[2][tid] + ps[3][tid];
    atomicAdd(&pool[tid], t);
  }
}

// ---------- final MLP ----------
__global__ void mlp_kernel(const float* __restrict__ pool,
                           const float* __restrict__ W1,
                           const float* __restrict__ b1,
                           const float* __restrict__ W2,
                           const float* __restrict__ b2,
                           float* __restrict__ out, float invN) {
  __shared__ float p[64], h[64];
  const int tid = threadIdx.x;
  if (tid < 64) p[tid] = pool[tid] * invN;
  __syncthreads();
  if (tid < 64) {
    float s = b1[tid];
    for (int k = 0; k < 64; k++) s = fmaf(p[k], W1[k * 64 + tid], s);
    h[tid] = fmaxf(s, 0.f);
  }
  __syncthreads();
  float s = b2[tid];
  for (int k = 0; k < 64; k++) s = fmaf(h[k], W2[k * 128 + tid], s);
  out[tid] = s;
}

extern "C" void kernel_launch(void* const* d_in, const int* in_sizes, int n_in,
                              void* d_out, int out_size, void* d_ws,
                              size_t ws_size, hipStream_t stream) {
  const int*   an  = (const int*)d_in[0];
  const int*   ei  = (const int*)d_in[3];
  const float* emb = (const float*)d_in[4];
  const float* Wl  = (const float*)d_in[5];
  const float* bl  = (const float*)d_in[6];
  const float* Wg  = (const float*)d_in[7];
  const float* bg  = (const float*)d_in[8];
  const float* W1  = (const float*)d_in[9];
  const float* b1  = (const float*)d_in[10];
  const float* W2  = (const float*)d_in[11];
  const float* b2  = (const float*)d_in[12];
  float* out = (float*)d_out;

  const int N = in_sizes[0];
  const int E = in_sizes[3] / 2;
  const int* row = ei;
  const int* col = ei + E;
  const int nbuck = (N + BROWS - 1) >> BSHIFT;

  const size_t NH = (size_t)N * H;
  char* ws = (char*)d_ws;
  ushort*   x    = (ushort*)(ws);
  float*    gr   = (float*)(ws + NH * 2);
  uint32_t* glpk = (uint32_t*)(ws + NH * 2 + NH * 4);
  char* p = ws + NH * 2 + NH * 4 + NH * 4;
  int*    offs   = (int*)p;    p += ((size_t)N + 1) * 4;
  int*    cols   = (int*)p;    p += (size_t)E * 4;
  int*    bcnt   = (int*)p;    p += 4096;
  int*    bstart = (int*)p;    p += 4100;
  int*    bcur   = (int*)p;    p += 4096;
  uint2*  ebuf   = (uint2*)p;  p += (size_t)E * 8;
  bf16x8* wprep  = (bf16x8*)p; p += 4608 * 16;
  float*  bgs    = (float*)p;  p += 192 * 4;
  float*  pool   = (float*)p;

  prep_kernel<<<18, 256, 0, stream>>>(Wl, Wg, bg, wprep, bgs);

  // --- CSR build (edges identical every layer) ---
  hipMemsetAsync(bcnt, 0, (size_t)nbuck * 4, stream);
  bucket_hist_kernel<<<1024, 256, 0, stream>>>(row, bcnt, E, nbuck);
  bucket_scan_kernel<<<1, 1024, 0, stream>>>(bcnt, bstart, bcur, offs, pool,
                                             nbuck, N, E);
  bucket_scatter_kernel<<<(E + SCHUNK - 1) / SCHUNK, 256, 0, stream>>>(
      row, col, bcur, ebuf, E, nbuck);
  csr_build_kernel<<<nbuck, 256, 0, stream>>>(ebuf, bstart, offs, cols, N);

  const int mmGrid = (N + 63) / 64;
  const int aggGrid = (N + 3) / 4;
  for (int l = 0; l < 3; l++) {
    const bf16x8* wp  = wprep + (size_t)l * 1536;
    const float*  bll = bl + (size_t)l * H;
    const float*  bgl = bgs + (size_t)l * H;
    if (l == 0)
      node_mm3_mfma<true><<<mmGrid, 256, 0, stream>>>(x, an, emb, wp, bll, bgl,
                                                      gr, glpk, N);
    else
      node_mm3_mfma<false><<<mmGrid, 256, 0, stream>>>(x, an, emb, wp, bll, bgl,
                                                       gr, glpk, N);
    agg_kernel<<<aggGrid, 256, 0, stream>>>(gr, glpk, offs, cols, x, N);
  }

  pool_kernel<<<1024, 256, 0, stream>>>(x, pool, N);
  mlp_kernel<<<1, 128, 0, stream>>>(pool, W1, b1, W2, b2, out, 1.0f / (float)N);
}